// Round 15
// baseline (541.954 us; speedup 1.0000x reference)
//
#include <hip/hip_runtime.h>

#define N_NODES   50000
#define N_EDGES   800000
#define G_GRAPHS  512
#define D_IN      10
#define D_CL      6
#define HID       64
#define NH        4
#define C1        256   // NH*HID
#define D_OUT     4
#define BN_EPS    1e-5f
#define CNT_PAD   53248  // 52*1024, padded count buffer for vectorized scan
#define NB_N1     782    // node1 sub-grid: 782*64 = 50048 >= 50000
#define NB_HIST   391    // hist sub-grid: 391*2048 = 800768 >= 800000 (8 edges/thread)

typedef unsigned short ushort_t;
typedef unsigned int uint_t;

__device__ __forceinline__ float leaky(float x){ return x > 0.f ? x : 0.2f*x; }
__device__ __forceinline__ ushort_t f2bf(float f){
  unsigned u = __float_as_uint(f);
  return (ushort_t)((u + 0x7fffu + ((u >> 16) & 1u)) >> 16);
}
__device__ __forceinline__ float bflo(uint_t u){ return __uint_as_float(u << 16); }
__device__ __forceinline__ float bfhi(uint_t u){ return __uint_as_float(u & 0xffff0000u); }
__device__ __forceinline__ uint_t pack2(float a, float b){
  return (uint_t)f2bf(a) | ((uint_t)f2bf(b) << 16);
}

// ---------------- K_pre: grid-fused {h1 = x@W1 + analytic logits} || {8-edge/thread hist+rank} ----------------
__global__ __launch_bounds__(256) void k_pre(const float* __restrict__ x,
    const float* __restrict__ W1, const float* __restrict__ a1s, const float* __restrict__ a1d,
    ushort_t* __restrict__ h1b, float* __restrict__ es1, float* __restrict__ ed1,
    const int* __restrict__ dstE, int* __restrict__ cnt, int* __restrict__ rank){
  if (blockIdx.x >= NB_N1){
    int base = (blockIdx.x - NB_N1)*2048 + threadIdx.x;
    #pragma unroll
    for (int u = 0; u < 8; ++u){
      int e = base + u*256;
      if (e < N_EDGES){
        rank[e] = atomicAdd(&cnt[dstE[e]], 1);
      }
    }
    return;
  }
  __shared__ float As[64][12];          // x tile, pad 10->12
  __shared__ float ahat[2][D_IN][NH];
  int t = threadIdx.x;
  long i0 = (long)blockIdx.x * 64;
  for (int idx = t; idx < 64*D_IN; idx += 256){
    int r = idx / D_IN, k = idx - r*D_IN;
    long gi = i0 + r;
    As[r][k] = (gi < N_NODES) ? x[gi*D_IN + k] : 0.f;
  }
  int cp = t & 127, half = t >> 7;
  float w1r0[D_IN], w1r1[D_IN];
  #pragma unroll
  for (int k = 0; k < D_IN; ++k){
    float2 v = *(const float2*)&W1[k*C1 + 2*cp];
    w1r0[k] = v.x; w1r1[k] = v.y;
  }
  if (t < 2*D_IN*NH){                  // 80 threads compute ahat (from global; no LDS conflicts)
    int which = (t >= D_IN*NH) ? 1 : 0;
    int r = which ? t - D_IN*NH : t;
    int k = r >> 2, h = r & 3;
    const float* av = which ? a1d : a1s;
    const float* wrow = &W1[k*C1 + h*64];
    const float* arow = &av[h*64];
    float s = 0.f;
    #pragma unroll
    for (int d = 0; d < 64; d += 4){
      float4 wv = *(const float4*)&wrow[d];
      float4 avv = *(const float4*)&arow[d];
      s += wv.x*avv.x + wv.y*avv.y + wv.z*avv.z + wv.w*avv.w;
    }
    ahat[which][k][h] = s;
  }
  __syncthreads();
  uint_t* h1u = (uint_t*)h1b;
  for (int r = half; r < 64; r += 2){
    long gi = i0 + r;
    if (gi >= N_NODES) break;
    float acc0 = 0.f, acc1 = 0.f;
    #pragma unroll
    for (int k = 0; k < D_IN; ++k){
      float xv = As[r][k];
      acc0 += xv*w1r0[k];
      acc1 += xv*w1r1[k];
    }
    h1u[gi*128 + cp] = pack2(acc0, acc1);
  }
  {
    int nn = t >> 2, h = t & 3;
    long gi = i0 + nn;
    if (gi < N_NODES){
      float s = 0.f, d_ = 0.f;
      #pragma unroll
      for (int k = 0; k < D_IN; ++k){
        float xv = As[nn][k];
        s  += xv*ahat[0][k][h];
        d_ += xv*ahat[1][k][h];
      }
      es1[gi*NH + h] = s;
      ed1[gi*NH + h] = d_;
    }
  }
}

// single-block vectorized exclusive scan of cnt -> off
__global__ __launch_bounds__(1024) void k_scan(const int* __restrict__ cnt, int* __restrict__ off){
  __shared__ int sh[1024];
  int t = threadIdx.x;
  int4 v[13];
  const int4* c4 = (const int4*)cnt;
  int base4 = t*13;
  int tsum = 0;
  #pragma unroll
  for (int k = 0; k < 13; ++k){
    v[k] = c4[base4 + k];
    tsum += v[k].x + v[k].y + v[k].z + v[k].w;
  }
  sh[t] = tsum;
  __syncthreads();
  for (int o = 1; o < 1024; o <<= 1){
    int xv = (t >= o) ? sh[t-o] : 0;
    __syncthreads();
    sh[t] += xv;
    __syncthreads();
  }
  int run = sh[t] - tsum;
  int4* o4 = (int4*)off;
  #pragma unroll
  for (int k = 0; k < 13; ++k){
    int i = t*52 + k*4;
    int4 w_;
    w_.x = run; run += v[k].x;
    w_.y = run; run += v[k].y;
    w_.z = run; run += v[k].z;
    w_.w = run; run += v[k].w;
    if (i + 3 < N_NODES) o4[base4 + k] = w_;
    else {
      if (i+0 < N_NODES) off[i+0] = w_.x;
      if (i+1 < N_NODES) off[i+1] = w_.y;
      if (i+2 < N_NODES) off[i+2] = w_.z;
      if (i+3 < N_NODES) off[i+3] = w_.w;
    }
  }
  if (t == 0) off[N_NODES] = N_EDGES;
}

// atomic-free scatter, 4 edges/thread
__global__ __launch_bounds__(256) void k_scatter(const int* __restrict__ src, const int* __restrict__ dst,
                          const int* __restrict__ rank, const int* __restrict__ off,
                          int* __restrict__ csr){
  int base = blockIdx.x*1024 + threadIdx.x;
  #pragma unroll
  for (int u = 0; u < 4; ++u){
    int e = base + u*256;
    if (e < N_EDGES) csr[off[dst[e]] + rank[e]] = src[e];
  }
}

// ---------------- K3: layer-1 GAT aggregation ----------------
__global__ __launch_bounds__(256) void k_agg1(const ushort_t* __restrict__ h1b,
    const float* __restrict__ es1, const float* __restrict__ ed1,
    const int* __restrict__ off, const int* __restrict__ csr,
    const float* __restrict__ b1, ushort_t* __restrict__ y1b){
  int lane = threadIdx.x & 63, wid = threadIdx.x >> 6;
  int i = blockIdx.x*4 + wid;
  if (i >= N_NODES) return;
  int lh = lane & 31, hf = lane >> 5;
  int headO = lh >> 3;
  int h    = lane & 3;
  int e    = lane >> 2;
  float4 edv4 = *(const float4*)&ed1[i*NH];
  float4 esv4 = *(const float4*)&es1[i*NH];
  float edh = (headO==0)?edv4.x:(headO==1)?edv4.y:(headO==2)?edv4.z:edv4.w;
  float esS = (headO==0)?esv4.x:(headO==1)?esv4.y:(headO==2)?esv4.z:esv4.w;
  float edw = (h==0)?edv4.x:(h==1)?edv4.y:(h==2)?edv4.z:edv4.w;
  int start = off[i], end = off[i+1];
  const uint4* h1v4 = (const uint4*)h1b;
  float wS = (hf == 0) ? __expf(leaky(esS + edh)) : 0.f;
  float ssum = wS;
  uint4 hv = h1v4[(long)i*32 + lh];
  float a0 = bflo(hv.x)*wS, a1 = bfhi(hv.x)*wS, a2 = bflo(hv.y)*wS, a3 = bfhi(hv.y)*wS;
  float a4 = bflo(hv.z)*wS, a5 = bfhi(hv.z)*wS, a6 = bflo(hv.w)*wS, a7 = bfhi(hv.w)*wS;
  for (int j0 = start; j0 < end; j0 += 16){
    int nj = end - j0; if (nj > 16) nj = 16;
    int ce = (e < nj) ? e : nj - 1;
    int sE = csr[j0 + ce];
    float wv = (e < nj) ? __expf(leaky(es1[sE*NH + h] + edw)) : 0.f;
    int jj = 0;
    for (; jj + 8 <= nj; jj += 8){
      int c0 = (jj+0+hf)<<2, c1 = (jj+2+hf)<<2, c2 = (jj+4+hf)<<2, c3 = (jj+6+hf)<<2;
      int s0 = __shfl(sE, c0);
      int s1 = __shfl(sE, c1);
      int s2 = __shfl(sE, c2);
      int s3 = __shfl(sE, c3);
      uint4 r0 = h1v4[(long)s0*32 + lh];
      uint4 r1 = h1v4[(long)s1*32 + lh];
      uint4 r2 = h1v4[(long)s2*32 + lh];
      uint4 r3 = h1v4[(long)s3*32 + lh];
      float w0 = __shfl(wv, c0 | headO);
      float w1 = __shfl(wv, c1 | headO);
      float w2 = __shfl(wv, c2 | headO);
      float w3 = __shfl(wv, c3 | headO);
      a0 += bflo(r0.x)*w0; a1 += bfhi(r0.x)*w0; a2 += bflo(r0.y)*w0; a3 += bfhi(r0.y)*w0;
      a4 += bflo(r0.z)*w0; a5 += bfhi(r0.z)*w0; a6 += bflo(r0.w)*w0; a7 += bfhi(r0.w)*w0;
      a0 += bflo(r1.x)*w1; a1 += bfhi(r1.x)*w1; a2 += bflo(r1.y)*w1; a3 += bfhi(r1.y)*w1;
      a4 += bflo(r1.z)*w1; a5 += bfhi(r1.z)*w1; a6 += bflo(r1.w)*w1; a7 += bfhi(r1.w)*w1;
      a0 += bflo(r2.x)*w2; a1 += bfhi(r2.x)*w2; a2 += bflo(r2.y)*w2; a3 += bfhi(r2.y)*w2;
      a4 += bflo(r2.z)*w2; a5 += bfhi(r2.z)*w2; a6 += bflo(r2.w)*w2; a7 += bfhi(r2.w)*w2;
      a0 += bflo(r3.x)*w3; a1 += bfhi(r3.x)*w3; a2 += bflo(r3.y)*w3; a3 += bfhi(r3.y)*w3;
      a4 += bflo(r3.z)*w3; a5 += bfhi(r3.z)*w3; a6 += bflo(r3.w)*w3; a7 += bfhi(r3.w)*w3;
      ssum += w0 + w1 + w2 + w3;
    }
    for (; jj < nj; jj += 2){
      int slot = jj + hf;
      int slc = (slot < nj) ? slot : nj - 1;
      int cc = slc << 2;
      int s = __shfl(sE, cc);
      float w = __shfl(wv, cc | headO);
      if (slot >= nj) w = 0.f;
      uint4 r = h1v4[(long)s*32 + lh];
      a0 += bflo(r.x)*w; a1 += bfhi(r.x)*w; a2 += bflo(r.y)*w; a3 += bfhi(r.y)*w;
      a4 += bflo(r.z)*w; a5 += bfhi(r.z)*w; a6 += bflo(r.w)*w; a7 += bfhi(r.w)*w;
      ssum += w;
    }
  }
  a0 += __shfl_xor(a0,32); a1 += __shfl_xor(a1,32); a2 += __shfl_xor(a2,32); a3 += __shfl_xor(a3,32);
  a4 += __shfl_xor(a4,32); a5 += __shfl_xor(a5,32); a6 += __shfl_xor(a6,32); a7 += __shfl_xor(a7,32);
  ssum += __shfl_xor(ssum,32);
  if (hf == 0){
    float inv = 1.f/(ssum + 1e-16f);
    float4 bb0 = *(const float4*)&b1[8*lh];
    float4 bb1 = *(const float4*)&b1[8*lh+4];
    uint4 o;
    o.x = pack2(a0*inv + bb0.x, a1*inv + bb0.y);
    o.y = pack2(a2*inv + bb0.z, a3*inv + bb0.w);
    o.z = pack2(a4*inv + bb1.x, a5*inv + bb1.y);
    o.w = pack2(a6*inv + bb1.z, a7*inv + bb1.w);
    ((uint4*)y1b)[(long)i*32 + lh] = o;
  }
}

// ---------------- BN column stats (bf16 input, C1 channels) ----------------
__global__ __launch_bounds__(256) void k_colstats1(const ushort_t* __restrict__ y, float* __restrict__ st){
  const uint_t* yu = (const uint_t*)y;
  int c2 = threadIdx.x & 127, half = threadIdx.x >> 7;
  long r0 = (long)blockIdx.x * 128;
  float s0=0,q0=0,s1=0,q1=0;
  for (int r = half; r < 128; r += 2){
    long rr = r0 + r;
    if (rr < N_NODES){
      uint_t u = yu[rr*128 + c2];
      float a = bflo(u), b = bfhi(u);
      s0 += a; q0 += a*a; s1 += b; q1 += b*b;
    }
  }
  int c = c2*2;
  atomicAdd(&st[c], s0);      atomicAdd(&st[C1 + c], q0);
  atomicAdd(&st[c+1], s1);    atomicAdd(&st[C1 + c+1], q1);
}

// ---------------- BN column stats (bf16 input, HID channels) ----------------
__global__ __launch_bounds__(256) void k_colstats2b(const ushort_t* __restrict__ y, float* __restrict__ st){
  const uint_t* yu = (const uint_t*)y;
  int c2 = threadIdx.x & 31, rl = threadIdx.x >> 5;   // 8 rows in parallel
  long r0 = (long)blockIdx.x * 128;
  float s0=0,q0=0,s1=0,q1=0;
  for (int r = rl; r < 128; r += 8){
    long rr = r0 + r;
    if (rr < N_NODES){
      uint_t u = yu[rr*32 + c2];
      float a = bflo(u), b = bfhi(u);
      s0 += a; q0 += a*a; s1 += b; q1 += b*b;
    }
  }
  int c = c2*2;
  atomicAdd(&st[c], s0);        atomicAdd(&st[HID + c], q0);
  atomicAdd(&st[c+1], s1);      atomicAdd(&st[HID + c+1], q1);
}

// ---------------- K6: h2 = relu(bn(y1)) @ W2 (bf16 out) + fused es2/ed2; BN prep inlined ----------------
__global__ __launch_bounds__(256) void k_gemm2(const ushort_t* __restrict__ y1b, const float* __restrict__ W2,
    const float* __restrict__ st1, const float* __restrict__ g1, const float* __restrict__ be1,
    const float* __restrict__ a2s, const float* __restrict__ a2d,
    ushort_t* __restrict__ h2b, float* __restrict__ es2, float* __restrict__ ed2){
  __shared__ float As[64][68];
  __shared__ float Bs[64][64];
  __shared__ float as_s[HID], ad_s[HID];
  __shared__ float ss_s[2*C1];
  int t = threadIdx.x;
  if (t < HID){ as_s[t] = a2s[t]; ad_s[t] = a2d[t]; }
  {
    float mean = st1[t] / (float)N_NODES;
    float var  = st1[C1 + t] / (float)N_NODES - mean*mean;
    float sc = g1[t] * rsqrtf(var + BN_EPS);
    ss_s[t] = sc;
    ss_s[C1 + t] = be1[t] - mean*sc;
  }
  int tx = t & 15, ty = t >> 4;
  long i0 = (long)blockIdx.x * 64;
  float acc[4][4] = {};
  __syncthreads();
  for (int kc = 0; kc < C1; kc += 64){
    const uint_t* yu = (const uint_t*)y1b;
    for (int idx = t; idx < 64*32; idx += 256){
      int r = idx >> 5, k2 = idx & 31;
      long gi = i0 + r;
      int k = kc + k2*2;
      float v0 = 0.f, v1 = 0.f;
      if (gi < N_NODES){
        uint_t u = yu[gi*128 + (k >> 1)];
        v0 = fmaxf(bflo(u)*ss_s[k]   + ss_s[C1+k],   0.f);
        v1 = fmaxf(bfhi(u)*ss_s[k+1] + ss_s[C1+k+1], 0.f);
      }
      As[r][k2*2]   = v0;
      As[r][k2*2+1] = v1;
    }
    for (int idx = t; idx < 64*64; idx += 256){
      Bs[idx >> 6][idx & 63] = W2[(kc + (idx >> 6))*HID + (idx & 63)];
    }
    __syncthreads();
    #pragma unroll 4
    for (int kk = 0; kk < 64; kk += 4){
      float4 va0 = *(float4*)&As[4*ty+0][kk];
      float4 va1 = *(float4*)&As[4*ty+1][kk];
      float4 va2 = *(float4*)&As[4*ty+2][kk];
      float4 va3 = *(float4*)&As[4*ty+3][kk];
      float4 vb0 = *(float4*)&Bs[kk+0][4*tx];
      float4 vb1 = *(float4*)&Bs[kk+1][4*tx];
      float4 vb2 = *(float4*)&Bs[kk+2][4*tx];
      float4 vb3 = *(float4*)&Bs[kk+3][4*tx];
      acc[0][0] += va0.x*vb0.x + va0.y*vb1.x + va0.z*vb2.x + va0.w*vb3.x;
      acc[0][1] += va0.x*vb0.y + va0.y*vb1.y + va0.z*vb2.y + va0.w*vb3.y;
      acc[0][2] += va0.x*vb0.z + va0.y*vb1.z + va0.z*vb2.z + va0.w*vb3.z;
      acc[0][3] += va0.x*vb0.w + va0.y*vb1.w + va0.z*vb2.w + va0.w*vb3.w;
      acc[1][0] += va1.x*vb0.x + va1.y*vb1.x + va1.z*vb2.x + va1.w*vb3.x;
      acc[1][1] += va1.x*vb0.y + va1.y*vb1.y + va1.z*vb2.y + va1.w*vb3.y;
      acc[1][2] += va1.x*vb0.z + va1.y*vb1.z + va1.z*vb2.z + va1.w*vb3.z;
      acc[1][3] += va1.x*vb0.w + va1.y*vb1.w + va1.z*vb2.w + va1.w*vb3.w;
      acc[2][0] += va2.x*vb0.x + va2.y*vb1.x + va2.z*vb2.x + va2.w*vb3.x;
      acc[2][1] += va2.x*vb0.y + va2.y*vb1.y + va2.z*vb2.y + va2.w*vb3.y;
      acc[2][2] += va2.x*vb0.z + va2.y*vb1.z + va2.z*vb2.z + va2.w*vb3.z;
      acc[2][3] += va2.x*vb0.w + va2.y*vb1.w + va2.z*vb2.w + va2.w*vb3.w;
      acc[3][0] += va3.x*vb0.x + va3.y*vb1.x + va3.z*vb2.x + va3.w*vb3.x;
      acc[3][1] += va3.x*vb0.y + va3.y*vb1.y + va3.z*vb2.y + va3.w*vb3.y;
      acc[3][2] += va3.x*vb0.z + va3.y*vb1.z + va3.z*vb2.z + va3.w*vb3.z;
      acc[3][3] += va3.x*vb0.w + va3.y*vb1.w + va3.z*vb2.w + va3.w*vb3.w;
    }
    __syncthreads();
  }
  #pragma unroll
  for (int rr = 0; rr < 4; ++rr){
    long gi = i0 + 4*ty + rr;
    if (gi < N_NODES){
      uint_t p0 = pack2(acc[rr][0], acc[rr][1]);
      uint_t p1 = pack2(acc[rr][2], acc[rr][3]);
      *(uint2*)&h2b[gi*HID + 4*tx] = make_uint2(p0, p1);
      float ps = acc[rr][0]*as_s[4*tx+0] + acc[rr][1]*as_s[4*tx+1]
               + acc[rr][2]*as_s[4*tx+2] + acc[rr][3]*as_s[4*tx+3];
      float pd = acc[rr][0]*ad_s[4*tx+0] + acc[rr][1]*ad_s[4*tx+1]
               + acc[rr][2]*ad_s[4*tx+2] + acc[rr][3]*ad_s[4*tx+3];
      #pragma unroll
      for (int o = 8; o >= 1; o >>= 1){ ps += __shfl_xor(ps,o); pd += __shfl_xor(pd,o); }
      if (tx == 0){ es2[gi] = ps; ed2[gi] = pd; }
    }
  }
}

// ---------------- K7: layer-2 GAT aggregation (bf16 output) ----------------
__global__ __launch_bounds__(256) void k_agg2(const ushort_t* __restrict__ h2b,
    const float* __restrict__ es2, const float* __restrict__ ed2,
    const int* __restrict__ off, const int* __restrict__ csr,
    const float* __restrict__ b2, ushort_t* __restrict__ y2b){
  int lane = threadIdx.x & 63, wid = threadIdx.x >> 6;
  int i = blockIdx.x*4 + wid;
  if (i >= N_NODES) return;
  int lq = lane & 15, q = lane >> 4;
  float edv = ed2[i];
  int start = off[i], end = off[i+1];
  const uint2* h2u2 = (const uint2*)h2b;
  float a0, a1, a2, a3, ssum;
  {
    float wS = (q == 0) ? __expf(leaky(es2[i] + edv)) : 0.f;
    uint2 uS = h2u2[(long)i*16 + lq];
    a0 = bflo(uS.x)*wS; a1 = bfhi(uS.x)*wS; a2 = bflo(uS.y)*wS; a3 = bfhi(uS.y)*wS;
    ssum = wS;
  }
  for (int j0 = start; j0 < end; j0 += 64){
    int nj = end - j0; if (nj > 64) nj = 64;
    int ce = (lane < nj) ? lane : nj - 1;
    int sE = csr[j0 + ce];
    float wv = (lane < nj) ? __expf(leaky(es2[sE] + edv)) : 0.f;
    int jj = 0;
    for (; jj + 16 <= nj; jj += 16){
      int c0 = jj + q, c1 = jj + 4 + q, c2 = jj + 8 + q, c3 = jj + 12 + q;
      int s0 = __shfl(sE, c0);
      int s1 = __shfl(sE, c1);
      int s2 = __shfl(sE, c2);
      int s3 = __shfl(sE, c3);
      uint2 r0 = h2u2[(long)s0*16 + lq];
      uint2 r1 = h2u2[(long)s1*16 + lq];
      uint2 r2 = h2u2[(long)s2*16 + lq];
      uint2 r3 = h2u2[(long)s3*16 + lq];
      float w0 = __shfl(wv, c0);
      float w1 = __shfl(wv, c1);
      float w2 = __shfl(wv, c2);
      float w3 = __shfl(wv, c3);
      a0 += bflo(r0.x)*w0; a1 += bfhi(r0.x)*w0; a2 += bflo(r0.y)*w0; a3 += bfhi(r0.y)*w0;
      a0 += bflo(r1.x)*w1; a1 += bfhi(r1.x)*w1; a2 += bflo(r1.y)*w1; a3 += bfhi(r1.y)*w1;
      a0 += bflo(r2.x)*w2; a1 += bfhi(r2.x)*w2; a2 += bflo(r2.y)*w2; a3 += bfhi(r2.y)*w2;
      a0 += bflo(r3.x)*w3; a1 += bfhi(r3.x)*w3; a2 += bflo(r3.y)*w3; a3 += bfhi(r3.y)*w3;
      ssum += w0 + w1 + w2 + w3;
    }
    for (; jj < nj; jj += 4){
      int slot = jj + q;
      int slc = (slot < nj) ? slot : nj - 1;
      int s = __shfl(sE, slc);
      float w = __shfl(wv, slc);
      if (slot >= nj) w = 0.f;
      uint2 r = h2u2[(long)s*16 + lq];
      a0 += bflo(r.x)*w; a1 += bfhi(r.x)*w; a2 += bflo(r.y)*w; a3 += bfhi(r.y)*w;
      ssum += w;
    }
  }
  a0 += __shfl_xor(a0,16); a1 += __shfl_xor(a1,16); a2 += __shfl_xor(a2,16); a3 += __shfl_xor(a3,16);
  ssum += __shfl_xor(ssum,16);
  a0 += __shfl_xor(a0,32); a1 += __shfl_xor(a1,32); a2 += __shfl_xor(a2,32); a3 += __shfl_xor(a3,32);
  ssum += __shfl_xor(ssum,32);
  if (q == 0){
    float inv = 1.f/(ssum + 1e-16f);
    float4 bb = *(const float4*)&b2[4*lq];
    uint2 o;
    o.x = pack2(a0*inv + bb.x, a1*inv + bb.y);
    o.y = pack2(a2*inv + bb.z, a3*inv + bb.w);
    ((uint2*)y2b)[(long)i*16 + lq] = o;
  }
}

// ---------------- final: tiled GEMM (bf16 y2), BN2 prep + climber MLP inlined ----------------
__global__ __launch_bounds__(256) void k_final(const ushort_t* __restrict__ y2b,
    const float* __restrict__ st2, const float* __restrict__ g2, const float* __restrict__ be2,
    const int* __restrict__ batch,
    const float* __restrict__ cl, const float* __restrict__ Wc, const float* __restrict__ bc,
    const float* __restrict__ Wcl1, const float* __restrict__ bcl1,
    const float* __restrict__ Wcl2, const float* __restrict__ bcl2,
    float* __restrict__ out){
  __shared__ float As[64][132];
  __shared__ float Bs[128][64];
  __shared__ float ss2s[2*HID];
  __shared__ float b1s[HID];
  __shared__ float W2s[HID*D_OUT];
  __shared__ float Wcs[D_CL*HID];
  __shared__ float bcs[HID];
  int t = threadIdx.x;
  long i0 = (long)blockIdx.x * 64;
  if (t < HID){
    float mean = st2[t] / (float)N_NODES;
    float var  = st2[HID + t] / (float)N_NODES - mean*mean;
    float sc = g2[t] * rsqrtf(var + BN_EPS);
    ss2s[t] = sc;
    ss2s[HID + t] = be2[t] - mean*sc;
  }
  if (t >= 64 && t < 128) bcs[t-64] = bc[t-64];
  if (t >= 128 && t < 192) b1s[t-128] = bcl1[t-128];
  W2s[t] = Wcl2[t];
  for (int idx = t; idx < D_CL*HID; idx += 256) Wcs[idx] = Wc[idx];
  __syncthreads();
  const uint_t* y2u = (const uint_t*)y2b;
  #pragma unroll
  for (int ii = 0; ii < 8; ++ii){
    int idx = t + 256*ii;
    int r = idx >> 5, k2 = idx & 31;
    long gi = i0 + r;
    float v0 = 0.f, v1 = 0.f;
    if (gi < N_NODES){
      uint_t u = y2u[gi*32 + k2];
      v0 = bflo(u); v1 = bfhi(u);
    }
    int k = k2*2;
    As[r][k]   = fmaxf(v0*ss2s[k]   + ss2s[HID+k],   0.f);
    As[r][k+1] = fmaxf(v1*ss2s[k+1] + ss2s[HID+k+1], 0.f);
  }
  #pragma unroll
  for (int ii = 0; ii < 8; ++ii){
    int idx = t + 256*ii;
    int r = idx >> 5, k2 = idx & 31;
    long gi = i0 + r;
    int k = k2*2;
    float c0 = 0.f, c1 = 0.f;
    if (gi < N_NODES){
      int g = batch[gi];
      const float* cg = cl + (long)g*D_CL;
      c0 = bcs[k]; c1 = bcs[k+1];
      #pragma unroll
      for (int kk = 0; kk < D_CL; ++kk){
        float clv = cg[kk];
        c0 += clv*Wcs[kk*HID + k];
        c1 += clv*Wcs[kk*HID + k+1];
      }
      c0 = fmaxf(c0, 0.f); c1 = fmaxf(c1, 0.f);
    }
    As[r][HID + k]   = c0;
    As[r][HID + k+1] = c1;
  }
  #pragma unroll
  for (int ii = 0; ii < 8; ++ii){
    int idx = t + 256*ii;
    int kk = idx >> 4, c4 = idx & 15;
    *(float4*)&Bs[kk][c4*4] = *(const float4*)&Wcl1[kk*64 + c4*4];
  }
  __syncthreads();
  int tx = t & 15, ty = t >> 4;
  float acc[4][4] = {};
  #pragma unroll 4
  for (int kk = 0; kk < 2*HID; kk += 4){
    float4 a0 = *(float4*)&As[4*ty+0][kk];
    float4 a1 = *(float4*)&As[4*ty+1][kk];
    float4 a2 = *(float4*)&As[4*ty+2][kk];
    float4 a3 = *(float4*)&As[4*ty+3][kk];
    float4 b0 = *(float4*)&Bs[kk+0][4*tx];
    float4 b1 = *(float4*)&Bs[kk+1][4*tx];
    float4 b2 = *(float4*)&Bs[kk+2][4*tx];
    float4 b3 = *(float4*)&Bs[kk+3][4*tx];
    acc[0][0] += a0.x*b0.x + a0.y*b1.x + a0.z*b2.x + a0.w*b3.x;
    acc[0][1] += a0.x*b0.y + a0.y*b1.y + a0.z*b2.y + a0.w*b3.y;
    acc[0][2] += a0.x*b0.z + a0.y*b1.z + a0.z*b2.z + a0.w*b3.z;
    acc[0][3] += a0.x*b0.w + a0.y*b1.w + a0.z*b2.w + a0.w*b3.w;
    acc[1][0] += a1.x*b0.x + a1.y*b1.x + a1.z*b2.x + a1.w*b3.x;
    acc[1][1] += a1.x*b0.y + a1.y*b1.y + a1.z*b2.y + a1.w*b3.y;
    acc[1][2] += a1.x*b0.z + a1.y*b1.z + a1.z*b2.z + a1.w*b3.z;
    acc[1][3] += a1.x*b0.w + a1.y*b1.w + a1.z*b2.w + a1.w*b3.w;
    acc[2][0] += a2.x*b0.x + a2.y*b1.x + a2.z*b2.x + a2.w*b3.x;
    acc[2][1] += a2.x*b0.y + a2.y*b1.y + a2.z*b2.y + a2.w*b3.y;
    acc[2][2] += a2.x*b0.z + a2.y*b1.z + a2.z*b2.z + a2.w*b3.z;
    acc[2][3] += a2.x*b0.w + a2.y*b1.w + a2.z*b2.w + a2.w*b3.w;
    acc[3][0] += a3.x*b0.x + a3.y*b1.x + a3.z*b2.x + a3.w*b3.x;
    acc[3][1] += a3.x*b0.y + a3.y*b1.y + a3.z*b2.y + a3.w*b3.y;
    acc[3][2] += a3.x*b0.z + a3.y*b1.z + a3.z*b2.z + a3.w*b3.z;
    acc[3][3] += a3.x*b0.w + a3.y*b1.w + a3.z*b2.w + a3.w*b3.w;
  }
  float p[4][4];
  #pragma unroll
  for (int r = 0; r < 4; ++r){
    #pragma unroll
    for (int c = 0; c < 4; ++c)
      acc[r][c] = fmaxf(acc[r][c] + b1s[4*tx+c], 0.f);
    #pragma unroll
    for (int oc = 0; oc < 4; ++oc){
      p[r][oc] = acc[r][0]*W2s[(4*tx+0)*4+oc] + acc[r][1]*W2s[(4*tx+1)*4+oc]
               + acc[r][2]*W2s[(4*tx+2)*4+oc] + acc[r][3]*W2s[(4*tx+3)*4+oc];
    }
  }
  #pragma unroll
  for (int o = 8; o >= 1; o >>= 1){
    #pragma unroll
    for (int r = 0; r < 4; ++r){
      p[r][0] += __shfl_xor(p[r][0], o);
      p[r][1] += __shfl_xor(p[r][1], o);
      p[r][2] += __shfl_xor(p[r][2], o);
      p[r][3] += __shfl_xor(p[r][3], o);
    }
  }
  if (tx == 0){
    float4 bb = *(const float4*)bcl2;
    #pragma unroll
    for (int r = 0; r < 4; ++r){
      long gi = i0 + 4*ty + r;
      if (gi < N_NODES){
        float4 o;
        o.x = p[r][0] + bb.x; o.y = p[r][1] + bb.y;
        o.z = p[r][2] + bb.z; o.w = p[r][3] + bb.w;
        *(float4*)&out[gi*4] = o;
      }
    }
  }
}

extern "C" void kernel_launch(void* const* d_in, const int* in_sizes, int n_in,
                              void* d_out, int out_size, void* d_ws, size_t ws_size,
                              hipStream_t stream){
  const float* x    = (const float*)d_in[0];
  const float* cl   = (const float*)d_in[1];
  const int*   ei   = (const int*)d_in[2];
  const int*   batch= (const int*)d_in[3];
  const float* W1   = (const float*)d_in[4];
  const float* a1s  = (const float*)d_in[5];
  const float* a1d  = (const float*)d_in[6];
  const float* b1   = (const float*)d_in[7];
  const float* g1   = (const float*)d_in[8];
  const float* be1  = (const float*)d_in[9];
  const float* W2   = (const float*)d_in[10];
  const float* a2s  = (const float*)d_in[11];
  const float* a2d  = (const float*)d_in[12];
  const float* b2   = (const float*)d_in[13];
  const float* g2   = (const float*)d_in[14];
  const float* be2  = (const float*)d_in[15];
  const float* Wc   = (const float*)d_in[16];
  const float* bc   = (const float*)d_in[17];
  const float* Wcl1 = (const float*)d_in[18];
  const float* bcl1 = (const float*)d_in[19];
  const float* Wcl2 = (const float*)d_in[20];
  const float* bcl2 = (const float*)d_in[21];
  const int* srcE = ei;
  const int* dstE = ei + N_EDGES;
  float* out = (float*)d_out;

  char* w = (char*)d_ws;
  auto take = [&](size_t bytes)->char*{ char* p = w; w += (bytes + 255) & ~(size_t)255; return p; };
  ushort_t* h1b = (ushort_t*)take((size_t)50048*C1*2);     // padded to 782*64 rows
  ushort_t* y1b = (ushort_t*)take((size_t)N_NODES*C1*2);   // 25.6 MB bf16
  float* es1 = (float*)take((size_t)50048*NH*4);
  float* ed1 = (float*)take((size_t)50048*NH*4);
  float* es2 = (float*)take((size_t)N_NODES*4);
  float* ed2 = (float*)take((size_t)N_NODES*4);
  float* st  = (float*)take((2*C1 + 2*HID)*4);   // 2560 B, contiguous with cnt -> single memset
  int* cnt  = (int*)take((size_t)CNT_PAD*4);
  int* off  = (int*)take((size_t)(CNT_PAD+16)*4);
  int* csr  = (int*)take((size_t)N_EDGES*4);
  int* rank = (int*)take((size_t)N_EDGES*4);
  float* st1 = st;
  float* st2 = st + 2*C1;
  // alias into dead h1b region after k_agg1: h2b (6.4 MB) at 0, y2b (6.4 MB) at +8 MB
  ushort_t* h2b = h1b;
  ushort_t* y2b = (ushort_t*)((char*)h1b + ((size_t)8 << 20));

  // st (2560 B) immediately followed by cnt: one memset covers both
  hipMemsetAsync(st, 0, (size_t)(2*C1 + 2*HID)*4 + (size_t)CNT_PAD*4, stream);

  k_pre<<<NB_N1 + NB_HIST, 256, 0, stream>>>(x, W1, a1s, a1d, h1b, es1, ed1, dstE, cnt, rank);
  k_scan<<<1, 1024, 0, stream>>>(cnt, off);
  k_scatter<<<(N_EDGES + 1023)/1024, 256, 0, stream>>>(srcE, dstE, rank, off, csr);

  k_agg1<<<(N_NODES+3)/4, 256, 0, stream>>>(h1b, es1, ed1, off, csr, b1, y1b);
  k_colstats1<<<(N_NODES+127)/128, 256, 0, stream>>>(y1b, st1);
  k_gemm2<<<(N_NODES+63)/64, 256, 0, stream>>>(y1b, W2, st1, g1, be1, a2s, a2d, h2b, es2, ed2);
  k_agg2<<<(N_NODES+3)/4, 256, 0, stream>>>(h2b, es2, ed2, off, csr, b2, y2b);
  k_colstats2b<<<(N_NODES+127)/128, 256, 0, stream>>>(y2b, st2);
  k_final<<<(N_NODES+63)/64, 256, 0, stream>>>(y2b, st2, g2, be2, batch, cl, Wc, bc, Wcl1, bcl1, Wcl2, bcl2, out);
}

// Round 16
// 356.102 us; speedup vs baseline: 1.5219x; 1.5219x over previous
//
#include <hip/hip_runtime.h>

#define N_NODES   50000
#define N_EDGES   800000
#define G_GRAPHS  512
#define D_IN      10
#define D_CL      6
#define HID       64
#define NH        4
#define C1        256   // NH*HID
#define D_OUT     4
#define BN_EPS    1e-5f
#define CNT_PAD   53248  // 52*1024, padded count buffer for vectorized scan
#define NB_N1     782    // node1 sub-grid: 782*64 = 50048 >= 50000
#define NB_HIST   391    // hist sub-grid: 391*2048 = 800768 >= 800000 (8 edges/thread)
#define NB_CS     96     // colstats blocks: per-address atomic chain = 96 (vs 782 before)

typedef unsigned short ushort_t;
typedef unsigned int uint_t;

__device__ __forceinline__ float leaky(float x){ return x > 0.f ? x : 0.2f*x; }
__device__ __forceinline__ ushort_t f2bf(float f){
  unsigned u = __float_as_uint(f);
  return (ushort_t)((u + 0x7fffu + ((u >> 16) & 1u)) >> 16);
}
__device__ __forceinline__ float bflo(uint_t u){ return __uint_as_float(u << 16); }
__device__ __forceinline__ float bfhi(uint_t u){ return __uint_as_float(u & 0xffff0000u); }
__device__ __forceinline__ uint_t pack2(float a, float b){
  return (uint_t)f2bf(a) | ((uint_t)f2bf(b) << 16);
}

// ---------------- K_pre: grid-fused {h1 = x@W1 + analytic logits} || {8-edge/thread hist+rank} ----------------
__global__ __launch_bounds__(256) void k_pre(const float* __restrict__ x,
    const float* __restrict__ W1, const float* __restrict__ a1s, const float* __restrict__ a1d,
    ushort_t* __restrict__ h1b, float* __restrict__ es1, float* __restrict__ ed1,
    const int* __restrict__ dstE, int* __restrict__ cnt, int* __restrict__ rank){
  if (blockIdx.x >= NB_N1){
    int base = (blockIdx.x - NB_N1)*2048 + threadIdx.x;
    #pragma unroll
    for (int u = 0; u < 8; ++u){
      int e = base + u*256;
      if (e < N_EDGES){
        rank[e] = atomicAdd(&cnt[dstE[e]], 1);
      }
    }
    return;
  }
  __shared__ float As[64][12];          // x tile, pad 10->12
  __shared__ float ahat[2][D_IN][NH];
  int t = threadIdx.x;
  long i0 = (long)blockIdx.x * 64;
  for (int idx = t; idx < 64*D_IN; idx += 256){
    int r = idx / D_IN, k = idx - r*D_IN;
    long gi = i0 + r;
    As[r][k] = (gi < N_NODES) ? x[gi*D_IN + k] : 0.f;
  }
  int cp = t & 127, half = t >> 7;
  float w1r0[D_IN], w1r1[D_IN];
  #pragma unroll
  for (int k = 0; k < D_IN; ++k){
    float2 v = *(const float2*)&W1[k*C1 + 2*cp];
    w1r0[k] = v.x; w1r1[k] = v.y;
  }
  if (t < 2*D_IN*NH){                  // 80 threads compute ahat (from global; no LDS conflicts)
    int which = (t >= D_IN*NH) ? 1 : 0;
    int r = which ? t - D_IN*NH : t;
    int k = r >> 2, h = r & 3;
    const float* av = which ? a1d : a1s;
    const float* wrow = &W1[k*C1 + h*64];
    const float* arow = &av[h*64];
    float s = 0.f;
    #pragma unroll
    for (int d = 0; d < 64; d += 4){
      float4 wv = *(const float4*)&wrow[d];
      float4 avv = *(const float4*)&arow[d];
      s += wv.x*avv.x + wv.y*avv.y + wv.z*avv.z + wv.w*avv.w;
    }
    ahat[which][k][h] = s;
  }
  __syncthreads();
  uint_t* h1u = (uint_t*)h1b;
  for (int r = half; r < 64; r += 2){
    long gi = i0 + r;
    if (gi >= N_NODES) break;
    float acc0 = 0.f, acc1 = 0.f;
    #pragma unroll
    for (int k = 0; k < D_IN; ++k){
      float xv = As[r][k];
      acc0 += xv*w1r0[k];
      acc1 += xv*w1r1[k];
    }
    h1u[gi*128 + cp] = pack2(acc0, acc1);
  }
  {
    int nn = t >> 2, h = t & 3;
    long gi = i0 + nn;
    if (gi < N_NODES){
      float s = 0.f, d_ = 0.f;
      #pragma unroll
      for (int k = 0; k < D_IN; ++k){
        float xv = As[nn][k];
        s  += xv*ahat[0][k][h];
        d_ += xv*ahat[1][k][h];
      }
      es1[gi*NH + h] = s;
      ed1[gi*NH + h] = d_;
    }
  }
}

// single-block vectorized exclusive scan of cnt -> off
__global__ __launch_bounds__(1024) void k_scan(const int* __restrict__ cnt, int* __restrict__ off){
  __shared__ int sh[1024];
  int t = threadIdx.x;
  int4 v[13];
  const int4* c4 = (const int4*)cnt;
  int base4 = t*13;
  int tsum = 0;
  #pragma unroll
  for (int k = 0; k < 13; ++k){
    v[k] = c4[base4 + k];
    tsum += v[k].x + v[k].y + v[k].z + v[k].w;
  }
  sh[t] = tsum;
  __syncthreads();
  for (int o = 1; o < 1024; o <<= 1){
    int xv = (t >= o) ? sh[t-o] : 0;
    __syncthreads();
    sh[t] += xv;
    __syncthreads();
  }
  int run = sh[t] - tsum;
  int4* o4 = (int4*)off;
  #pragma unroll
  for (int k = 0; k < 13; ++k){
    int i = t*52 + k*4;
    int4 w_;
    w_.x = run; run += v[k].x;
    w_.y = run; run += v[k].y;
    w_.z = run; run += v[k].z;
    w_.w = run; run += v[k].w;
    if (i + 3 < N_NODES) o4[base4 + k] = w_;
    else {
      if (i+0 < N_NODES) off[i+0] = w_.x;
      if (i+1 < N_NODES) off[i+1] = w_.y;
      if (i+2 < N_NODES) off[i+2] = w_.z;
      if (i+3 < N_NODES) off[i+3] = w_.w;
    }
  }
  if (t == 0) off[N_NODES] = N_EDGES;
}

// atomic-free scatter, 4 edges/thread
__global__ __launch_bounds__(256) void k_scatter(const int* __restrict__ src, const int* __restrict__ dst,
                          const int* __restrict__ rank, const int* __restrict__ off,
                          int* __restrict__ csr){
  int base = blockIdx.x*1024 + threadIdx.x;
  #pragma unroll
  for (int u = 0; u < 4; ++u){
    int e = base + u*256;
    if (e < N_EDGES) csr[off[dst[e]] + rank[e]] = src[e];
  }
}

// ---------------- K3: layer-1 GAT aggregation ----------------
__global__ __launch_bounds__(256) void k_agg1(const ushort_t* __restrict__ h1b,
    const float* __restrict__ es1, const float* __restrict__ ed1,
    const int* __restrict__ off, const int* __restrict__ csr,
    const float* __restrict__ b1, ushort_t* __restrict__ y1b){
  int lane = threadIdx.x & 63, wid = threadIdx.x >> 6;
  int i = blockIdx.x*4 + wid;
  if (i >= N_NODES) return;
  int lh = lane & 31, hf = lane >> 5;
  int headO = lh >> 3;
  int h    = lane & 3;
  int e    = lane >> 2;
  float4 edv4 = *(const float4*)&ed1[i*NH];
  float4 esv4 = *(const float4*)&es1[i*NH];
  float edh = (headO==0)?edv4.x:(headO==1)?edv4.y:(headO==2)?edv4.z:edv4.w;
  float esS = (headO==0)?esv4.x:(headO==1)?esv4.y:(headO==2)?esv4.z:esv4.w;
  float edw = (h==0)?edv4.x:(h==1)?edv4.y:(h==2)?edv4.z:edv4.w;
  int start = off[i], end = off[i+1];
  const uint4* h1v4 = (const uint4*)h1b;
  float wS = (hf == 0) ? __expf(leaky(esS + edh)) : 0.f;
  float ssum = wS;
  uint4 hv = h1v4[(long)i*32 + lh];
  float a0 = bflo(hv.x)*wS, a1 = bfhi(hv.x)*wS, a2 = bflo(hv.y)*wS, a3 = bfhi(hv.y)*wS;
  float a4 = bflo(hv.z)*wS, a5 = bfhi(hv.z)*wS, a6 = bflo(hv.w)*wS, a7 = bfhi(hv.w)*wS;
  for (int j0 = start; j0 < end; j0 += 16){
    int nj = end - j0; if (nj > 16) nj = 16;
    int ce = (e < nj) ? e : nj - 1;
    int sE = csr[j0 + ce];
    float wv = (e < nj) ? __expf(leaky(es1[sE*NH + h] + edw)) : 0.f;
    int jj = 0;
    for (; jj + 8 <= nj; jj += 8){
      int c0 = (jj+0+hf)<<2, c1 = (jj+2+hf)<<2, c2 = (jj+4+hf)<<2, c3 = (jj+6+hf)<<2;
      int s0 = __shfl(sE, c0);
      int s1 = __shfl(sE, c1);
      int s2 = __shfl(sE, c2);
      int s3 = __shfl(sE, c3);
      uint4 r0 = h1v4[(long)s0*32 + lh];
      uint4 r1 = h1v4[(long)s1*32 + lh];
      uint4 r2 = h1v4[(long)s2*32 + lh];
      uint4 r3 = h1v4[(long)s3*32 + lh];
      float w0 = __shfl(wv, c0 | headO);
      float w1 = __shfl(wv, c1 | headO);
      float w2 = __shfl(wv, c2 | headO);
      float w3 = __shfl(wv, c3 | headO);
      a0 += bflo(r0.x)*w0; a1 += bfhi(r0.x)*w0; a2 += bflo(r0.y)*w0; a3 += bfhi(r0.y)*w0;
      a4 += bflo(r0.z)*w0; a5 += bfhi(r0.z)*w0; a6 += bflo(r0.w)*w0; a7 += bfhi(r0.w)*w0;
      a0 += bflo(r1.x)*w1; a1 += bfhi(r1.x)*w1; a2 += bflo(r1.y)*w1; a3 += bfhi(r1.y)*w1;
      a4 += bflo(r1.z)*w1; a5 += bfhi(r1.z)*w1; a6 += bflo(r1.w)*w1; a7 += bfhi(r1.w)*w1;
      a0 += bflo(r2.x)*w2; a1 += bfhi(r2.x)*w2; a2 += bflo(r2.y)*w2; a3 += bfhi(r2.y)*w2;
      a4 += bflo(r2.z)*w2; a5 += bfhi(r2.z)*w2; a6 += bflo(r2.w)*w2; a7 += bfhi(r2.w)*w2;
      a0 += bflo(r3.x)*w3; a1 += bfhi(r3.x)*w3; a2 += bflo(r3.y)*w3; a3 += bfhi(r3.y)*w3;
      a4 += bflo(r3.z)*w3; a5 += bfhi(r3.z)*w3; a6 += bflo(r3.w)*w3; a7 += bfhi(r3.w)*w3;
      ssum += w0 + w1 + w2 + w3;
    }
    for (; jj < nj; jj += 2){
      int slot = jj + hf;
      int slc = (slot < nj) ? slot : nj - 1;
      int cc = slc << 2;
      int s = __shfl(sE, cc);
      float w = __shfl(wv, cc | headO);
      if (slot >= nj) w = 0.f;
      uint4 r = h1v4[(long)s*32 + lh];
      a0 += bflo(r.x)*w; a1 += bfhi(r.x)*w; a2 += bflo(r.y)*w; a3 += bfhi(r.y)*w;
      a4 += bflo(r.z)*w; a5 += bfhi(r.z)*w; a6 += bflo(r.w)*w; a7 += bfhi(r.w)*w;
      ssum += w;
    }
  }
  a0 += __shfl_xor(a0,32); a1 += __shfl_xor(a1,32); a2 += __shfl_xor(a2,32); a3 += __shfl_xor(a3,32);
  a4 += __shfl_xor(a4,32); a5 += __shfl_xor(a5,32); a6 += __shfl_xor(a6,32); a7 += __shfl_xor(a7,32);
  ssum += __shfl_xor(ssum,32);
  if (hf == 0){
    float inv = 1.f/(ssum + 1e-16f);
    float4 bb0 = *(const float4*)&b1[8*lh];
    float4 bb1 = *(const float4*)&b1[8*lh+4];
    uint4 o;
    o.x = pack2(a0*inv + bb0.x, a1*inv + bb0.y);
    o.y = pack2(a2*inv + bb0.z, a3*inv + bb0.w);
    o.z = pack2(a4*inv + bb1.x, a5*inv + bb1.y);
    o.w = pack2(a6*inv + bb1.z, a7*inv + bb1.w);
    ((uint4*)y1b)[(long)i*32 + lh] = o;
  }
}

// ---------------- BN1 column stats (bf16, C1 channels): 96 blocks, 1 atomic/channel/block ----------------
__global__ __launch_bounds__(256) void k_colstats1(const ushort_t* __restrict__ y, float* __restrict__ st){
  __shared__ float cs[512];
  const uint_t* yu = (const uint_t*)y;
  int t = threadIdx.x;
  int col = t & 127, half = t >> 7;
  const int rpb = (N_NODES + NB_CS - 1)/NB_CS;   // 521
  int r0 = blockIdx.x * rpb;
  int r1 = r0 + rpb; if (r1 > N_NODES) r1 = N_NODES;
  float s0=0,q0=0,s1=0,q1=0;
  for (int r = r0 + half; r < r1; r += 2){
    uint_t u = yu[(long)r*128 + col];
    float a = bflo(u), b = bfhi(u);
    s0 += a; q0 += a*a; s1 += b; q1 += b*b;
  }
  if (half == 1){
    cs[col*4+0] = s0; cs[col*4+1] = q0; cs[col*4+2] = s1; cs[col*4+3] = q1;
  }
  __syncthreads();
  if (half == 0){
    s0 += cs[col*4+0]; q0 += cs[col*4+1]; s1 += cs[col*4+2]; q1 += cs[col*4+3];
    int c = col*2;
    atomicAdd(&st[c],   s0);  atomicAdd(&st[C1+c],   q0);
    atomicAdd(&st[c+1], s1);  atomicAdd(&st[C1+c+1], q1);
  }
}

// ---------------- BN2 column stats (f32, HID channels): 96 blocks, 1 atomic/channel/block ----------------
__global__ __launch_bounds__(256) void k_colstats2(const float* __restrict__ y, float* __restrict__ st){
  __shared__ float cs[HID*2*3];
  int t = threadIdx.x;
  int c = t & 63, qd = t >> 6;                   // 4 row-groups
  const int rpb = (N_NODES + NB_CS - 1)/NB_CS;   // 521
  int r0 = blockIdx.x * rpb;
  int r1 = r0 + rpb; if (r1 > N_NODES) r1 = N_NODES;
  float s=0,q=0;
  for (int r = r0 + qd; r < r1; r += 4){
    float v = y[(long)r*HID + c];
    s += v; q += v*v;
  }
  if (qd > 0){ cs[(qd-1)*128 + c*2] = s; cs[(qd-1)*128 + c*2+1] = q; }
  __syncthreads();
  if (qd == 0){
    s += cs[c*2]   + cs[128+c*2]   + cs[256+c*2];
    q += cs[c*2+1] + cs[128+c*2+1] + cs[256+c*2+1];
    atomicAdd(&st[c], s); atomicAdd(&st[HID+c], q);
  }
}

// ---------------- K6: h2 = relu(bn(y1)) @ W2 (bf16 out) + fused es2/ed2; BN prep inlined ----------------
__global__ __launch_bounds__(256) void k_gemm2(const ushort_t* __restrict__ y1b, const float* __restrict__ W2,
    const float* __restrict__ st1, const float* __restrict__ g1, const float* __restrict__ be1,
    const float* __restrict__ a2s, const float* __restrict__ a2d,
    ushort_t* __restrict__ h2b, float* __restrict__ es2, float* __restrict__ ed2){
  __shared__ float As[64][68];
  __shared__ float Bs[64][64];
  __shared__ float as_s[HID], ad_s[HID];
  __shared__ float ss_s[2*C1];
  int t = threadIdx.x;
  if (t < HID){ as_s[t] = a2s[t]; ad_s[t] = a2d[t]; }
  {
    float mean = st1[t] / (float)N_NODES;
    float var  = st1[C1 + t] / (float)N_NODES - mean*mean;
    float sc = g1[t] * rsqrtf(var + BN_EPS);
    ss_s[t] = sc;
    ss_s[C1 + t] = be1[t] - mean*sc;
  }
  int tx = t & 15, ty = t >> 4;
  long i0 = (long)blockIdx.x * 64;
  float acc[4][4] = {};
  __syncthreads();
  for (int kc = 0; kc < C1; kc += 64){
    const uint_t* yu = (const uint_t*)y1b;
    for (int idx = t; idx < 64*32; idx += 256){
      int r = idx >> 5, k2 = idx & 31;
      long gi = i0 + r;
      int k = kc + k2*2;
      float v0 = 0.f, v1 = 0.f;
      if (gi < N_NODES){
        uint_t u = yu[gi*128 + (k >> 1)];
        v0 = fmaxf(bflo(u)*ss_s[k]   + ss_s[C1+k],   0.f);
        v1 = fmaxf(bfhi(u)*ss_s[k+1] + ss_s[C1+k+1], 0.f);
      }
      As[r][k2*2]   = v0;
      As[r][k2*2+1] = v1;
    }
    for (int idx = t; idx < 64*64; idx += 256){
      Bs[idx >> 6][idx & 63] = W2[(kc + (idx >> 6))*HID + (idx & 63)];
    }
    __syncthreads();
    #pragma unroll 4
    for (int kk = 0; kk < 64; kk += 4){
      float4 va0 = *(float4*)&As[4*ty+0][kk];
      float4 va1 = *(float4*)&As[4*ty+1][kk];
      float4 va2 = *(float4*)&As[4*ty+2][kk];
      float4 va3 = *(float4*)&As[4*ty+3][kk];
      float4 vb0 = *(float4*)&Bs[kk+0][4*tx];
      float4 vb1 = *(float4*)&Bs[kk+1][4*tx];
      float4 vb2 = *(float4*)&Bs[kk+2][4*tx];
      float4 vb3 = *(float4*)&Bs[kk+3][4*tx];
      acc[0][0] += va0.x*vb0.x + va0.y*vb1.x + va0.z*vb2.x + va0.w*vb3.x;
      acc[0][1] += va0.x*vb0.y + va0.y*vb1.y + va0.z*vb2.y + va0.w*vb3.y;
      acc[0][2] += va0.x*vb0.z + va0.y*vb1.z + va0.z*vb2.z + va0.w*vb3.z;
      acc[0][3] += va0.x*vb0.w + va0.y*vb1.w + va0.z*vb2.w + va0.w*vb3.w;
      acc[1][0] += va1.x*vb0.x + va1.y*vb1.x + va1.z*vb2.x + va1.w*vb3.x;
      acc[1][1] += va1.x*vb0.y + va1.y*vb1.y + va1.z*vb2.y + va1.w*vb3.y;
      acc[1][2] += va1.x*vb0.z + va1.y*vb1.z + va1.z*vb2.z + va1.w*vb3.z;
      acc[1][3] += va1.x*vb0.w + va1.y*vb1.w + va1.z*vb2.w + va1.w*vb3.w;
      acc[2][0] += va2.x*vb0.x + va2.y*vb1.x + va2.z*vb2.x + va2.w*vb3.x;
      acc[2][1] += va2.x*vb0.y + va2.y*vb1.y + va2.z*vb2.y + va2.w*vb3.y;
      acc[2][2] += va2.x*vb0.z + va2.y*vb1.z + va2.z*vb2.z + va2.w*vb3.z;
      acc[2][3] += va2.x*vb0.w + va2.y*vb1.w + va2.z*vb2.w + va2.w*vb3.w;
      acc[3][0] += va3.x*vb0.x + va3.y*vb1.x + va3.z*vb2.x + va3.w*vb3.x;
      acc[3][1] += va3.x*vb0.y + va3.y*vb1.y + va3.z*vb2.y + va3.w*vb3.y;
      acc[3][2] += va3.x*vb0.z + va3.y*vb1.z + va3.z*vb2.z + va3.w*vb3.z;
      acc[3][3] += va3.x*vb0.w + va3.y*vb1.w + va3.z*vb2.w + va3.w*vb3.w;
    }
    __syncthreads();
  }
  #pragma unroll
  for (int rr = 0; rr < 4; ++rr){
    long gi = i0 + 4*ty + rr;
    if (gi < N_NODES){
      uint_t p0 = pack2(acc[rr][0], acc[rr][1]);
      uint_t p1 = pack2(acc[rr][2], acc[rr][3]);
      *(uint2*)&h2b[gi*HID + 4*tx] = make_uint2(p0, p1);
      float ps = acc[rr][0]*as_s[4*tx+0] + acc[rr][1]*as_s[4*tx+1]
               + acc[rr][2]*as_s[4*tx+2] + acc[rr][3]*as_s[4*tx+3];
      float pd = acc[rr][0]*ad_s[4*tx+0] + acc[rr][1]*ad_s[4*tx+1]
               + acc[rr][2]*ad_s[4*tx+2] + acc[rr][3]*ad_s[4*tx+3];
      #pragma unroll
      for (int o = 8; o >= 1; o >>= 1){ ps += __shfl_xor(ps,o); pd += __shfl_xor(pd,o); }
      if (tx == 0){ es2[gi] = ps; ed2[gi] = pd; }
    }
  }
}

// ---------------- K7: layer-2 GAT aggregation (f32 output) ----------------
__global__ __launch_bounds__(256) void k_agg2(const ushort_t* __restrict__ h2b,
    const float* __restrict__ es2, const float* __restrict__ ed2,
    const int* __restrict__ off, const int* __restrict__ csr,
    const float* __restrict__ b2, float* __restrict__ y2){
  int lane = threadIdx.x & 63, wid = threadIdx.x >> 6;
  int i = blockIdx.x*4 + wid;
  if (i >= N_NODES) return;
  int lq = lane & 15, q = lane >> 4;
  float edv = ed2[i];
  int start = off[i], end = off[i+1];
  const uint2* h2u2 = (const uint2*)h2b;
  float a0, a1, a2, a3, ssum;
  {
    float wS = (q == 0) ? __expf(leaky(es2[i] + edv)) : 0.f;
    uint2 uS = h2u2[(long)i*16 + lq];
    a0 = bflo(uS.x)*wS; a1 = bfhi(uS.x)*wS; a2 = bflo(uS.y)*wS; a3 = bfhi(uS.y)*wS;
    ssum = wS;
  }
  for (int j0 = start; j0 < end; j0 += 64){
    int nj = end - j0; if (nj > 64) nj = 64;
    int ce = (lane < nj) ? lane : nj - 1;
    int sE = csr[j0 + ce];
    float wv = (lane < nj) ? __expf(leaky(es2[sE] + edv)) : 0.f;
    int jj = 0;
    for (; jj + 16 <= nj; jj += 16){
      int c0 = jj + q, c1 = jj + 4 + q, c2 = jj + 8 + q, c3 = jj + 12 + q;
      int s0 = __shfl(sE, c0);
      int s1 = __shfl(sE, c1);
      int s2 = __shfl(sE, c2);
      int s3 = __shfl(sE, c3);
      uint2 r0 = h2u2[(long)s0*16 + lq];
      uint2 r1 = h2u2[(long)s1*16 + lq];
      uint2 r2 = h2u2[(long)s2*16 + lq];
      uint2 r3 = h2u2[(long)s3*16 + lq];
      float w0 = __shfl(wv, c0);
      float w1 = __shfl(wv, c1);
      float w2 = __shfl(wv, c2);
      float w3 = __shfl(wv, c3);
      a0 += bflo(r0.x)*w0; a1 += bfhi(r0.x)*w0; a2 += bflo(r0.y)*w0; a3 += bfhi(r0.y)*w0;
      a0 += bflo(r1.x)*w1; a1 += bfhi(r1.x)*w1; a2 += bflo(r1.y)*w1; a3 += bfhi(r1.y)*w1;
      a0 += bflo(r2.x)*w2; a1 += bfhi(r2.x)*w2; a2 += bflo(r2.y)*w2; a3 += bfhi(r2.y)*w2;
      a0 += bflo(r3.x)*w3; a1 += bfhi(r3.x)*w3; a2 += bflo(r3.y)*w3; a3 += bfhi(r3.y)*w3;
      ssum += w0 + w1 + w2 + w3;
    }
    for (; jj < nj; jj += 4){
      int slot = jj + q;
      int slc = (slot < nj) ? slot : nj - 1;
      int s = __shfl(sE, slc);
      float w = __shfl(wv, slc);
      if (slot >= nj) w = 0.f;
      uint2 r = h2u2[(long)s*16 + lq];
      a0 += bflo(r.x)*w; a1 += bfhi(r.x)*w; a2 += bflo(r.y)*w; a3 += bfhi(r.y)*w;
      ssum += w;
    }
  }
  a0 += __shfl_xor(a0,16); a1 += __shfl_xor(a1,16); a2 += __shfl_xor(a2,16); a3 += __shfl_xor(a3,16);
  ssum += __shfl_xor(ssum,16);
  a0 += __shfl_xor(a0,32); a1 += __shfl_xor(a1,32); a2 += __shfl_xor(a2,32); a3 += __shfl_xor(a3,32);
  ssum += __shfl_xor(ssum,32);
  if (q == 0){
    float inv = 1.f/(ssum + 1e-16f);
    float4 bb = *(const float4*)&b2[4*lq];
    float4 o;
    o.x = a0*inv + bb.x; o.y = a1*inv + bb.y;
    o.z = a2*inv + bb.z; o.w = a3*inv + bb.w;
    ((float4*)y2)[(long)i*16 + lq] = o;
  }
}

// ---------------- final: tiled GEMM, BN2 prep + climber MLP inlined ----------------
__global__ __launch_bounds__(256) void k_final(const float* __restrict__ y2,
    const float* __restrict__ st2, const float* __restrict__ g2, const float* __restrict__ be2,
    const int* __restrict__ batch,
    const float* __restrict__ cl, const float* __restrict__ Wc, const float* __restrict__ bc,
    const float* __restrict__ Wcl1, const float* __restrict__ bcl1,
    const float* __restrict__ Wcl2, const float* __restrict__ bcl2,
    float* __restrict__ out){
  __shared__ float As[64][132];
  __shared__ float Bs[128][64];
  __shared__ float ss2s[2*HID];
  __shared__ float b1s[HID];
  __shared__ float W2s[HID*D_OUT];
  __shared__ float Wcs[D_CL*HID];
  __shared__ float bcs[HID];
  int t = threadIdx.x;
  long i0 = (long)blockIdx.x * 64;
  if (t < HID){
    float mean = st2[t] / (float)N_NODES;
    float var  = st2[HID + t] / (float)N_NODES - mean*mean;
    float sc = g2[t] * rsqrtf(var + BN_EPS);
    ss2s[t] = sc;
    ss2s[HID + t] = be2[t] - mean*sc;
  }
  if (t >= 64 && t < 128) bcs[t-64] = bc[t-64];
  if (t >= 128 && t < 192) b1s[t-128] = bcl1[t-128];
  W2s[t] = Wcl2[t];
  for (int idx = t; idx < D_CL*HID; idx += 256) Wcs[idx] = Wc[idx];
  __syncthreads();
  const float2* y2v = (const float2*)y2;
  #pragma unroll
  for (int ii = 0; ii < 8; ++ii){
    int idx = t + 256*ii;
    int r = idx >> 5, k2 = idx & 31;
    long gi = i0 + r;
    float2 v = make_float2(0.f, 0.f);
    if (gi < N_NODES) v = y2v[gi*32 + k2];
    int k = k2*2;
    As[r][k]   = fmaxf(v.x*ss2s[k]   + ss2s[HID+k],   0.f);
    As[r][k+1] = fmaxf(v.y*ss2s[k+1] + ss2s[HID+k+1], 0.f);
  }
  #pragma unroll
  for (int ii = 0; ii < 8; ++ii){
    int idx = t + 256*ii;
    int r = idx >> 5, k2 = idx & 31;
    long gi = i0 + r;
    int k = k2*2;
    float c0 = 0.f, c1 = 0.f;
    if (gi < N_NODES){
      int g = batch[gi];
      const float* cg = cl + (long)g*D_CL;
      c0 = bcs[k]; c1 = bcs[k+1];
      #pragma unroll
      for (int kk = 0; kk < D_CL; ++kk){
        float clv = cg[kk];
        c0 += clv*Wcs[kk*HID + k];
        c1 += clv*Wcs[kk*HID + k+1];
      }
      c0 = fmaxf(c0, 0.f); c1 = fmaxf(c1, 0.f);
    }
    As[r][HID + k]   = c0;
    As[r][HID + k+1] = c1;
  }
  #pragma unroll
  for (int ii = 0; ii < 8; ++ii){
    int idx = t + 256*ii;
    int kk = idx >> 4, c4 = idx & 15;
    *(float4*)&Bs[kk][c4*4] = *(const float4*)&Wcl1[kk*64 + c4*4];
  }
  __syncthreads();
  int tx = t & 15, ty = t >> 4;
  float acc[4][4] = {};
  #pragma unroll 4
  for (int kk = 0; kk < 2*HID; kk += 4){
    float4 a0 = *(float4*)&As[4*ty+0][kk];
    float4 a1 = *(float4*)&As[4*ty+1][kk];
    float4 a2 = *(float4*)&As[4*ty+2][kk];
    float4 a3 = *(float4*)&As[4*ty+3][kk];
    float4 b0 = *(float4*)&Bs[kk+0][4*tx];
    float4 b1 = *(float4*)&Bs[kk+1][4*tx];
    float4 b2 = *(float4*)&Bs[kk+2][4*tx];
    float4 b3 = *(float4*)&Bs[kk+3][4*tx];
    acc[0][0] += a0.x*b0.x + a0.y*b1.x + a0.z*b2.x + a0.w*b3.x;
    acc[0][1] += a0.x*b0.y + a0.y*b1.y + a0.z*b2.y + a0.w*b3.y;
    acc[0][2] += a0.x*b0.z + a0.y*b1.z + a0.z*b2.z + a0.w*b3.z;
    acc[0][3] += a0.x*b0.w + a0.y*b1.w + a0.z*b2.w + a0.w*b3.w;
    acc[1][0] += a1.x*b0.x + a1.y*b1.x + a1.z*b2.x + a1.w*b3.x;
    acc[1][1] += a1.x*b0.y + a1.y*b1.y + a1.z*b2.y + a1.w*b3.y;
    acc[1][2] += a1.x*b0.z + a1.y*b1.z + a1.z*b2.z + a1.w*b3.z;
    acc[1][3] += a1.x*b0.w + a1.y*b1.w + a1.z*b2.w + a1.w*b3.w;
    acc[2][0] += a2.x*b0.x + a2.y*b1.x + a2.z*b2.x + a2.w*b3.x;
    acc[2][1] += a2.x*b0.y + a2.y*b1.y + a2.z*b2.y + a2.w*b3.y;
    acc[2][2] += a2.x*b0.z + a2.y*b1.z + a2.z*b2.z + a2.w*b3.z;
    acc[2][3] += a2.x*b0.w + a2.y*b1.w + a2.z*b2.w + a2.w*b3.w;
    acc[3][0] += a3.x*b0.x + a3.y*b1.x + a3.z*b2.x + a3.w*b3.x;
    acc[3][1] += a3.x*b0.y + a3.y*b1.y + a3.z*b2.y + a3.w*b3.y;
    acc[3][2] += a3.x*b0.z + a3.y*b1.z + a3.z*b2.z + a3.w*b3.z;
    acc[3][3] += a3.x*b0.w + a3.y*b1.w + a3.z*b2.w + a3.w*b3.w;
  }
  float p[4][4];
  #pragma unroll
  for (int r = 0; r < 4; ++r){
    #pragma unroll
    for (int c = 0; c < 4; ++c)
      acc[r][c] = fmaxf(acc[r][c] + b1s[4*tx+c], 0.f);
    #pragma unroll
    for (int oc = 0; oc < 4; ++oc){
      p[r][oc] = acc[r][0]*W2s[(4*tx+0)*4+oc] + acc[r][1]*W2s[(4*tx+1)*4+oc]
               + acc[r][2]*W2s[(4*tx+2)*4+oc] + acc[r][3]*W2s[(4*tx+3)*4+oc];
    }
  }
  #pragma unroll
  for (int o = 8; o >= 1; o >>= 1){
    #pragma unroll
    for (int r = 0; r < 4; ++r){
      p[r][0] += __shfl_xor(p[r][0], o);
      p[r][1] += __shfl_xor(p[r][1], o);
      p[r][2] += __shfl_xor(p[r][2], o);
      p[r][3] += __shfl_xor(p[r][3], o);
    }
  }
  if (tx == 0){
    float4 bb = *(const float4*)bcl2;
    #pragma unroll
    for (int r = 0; r < 4; ++r){
      long gi = i0 + 4*ty + r;
      if (gi < N_NODES){
        float4 o;
        o.x = p[r][0] + bb.x; o.y = p[r][1] + bb.y;
        o.z = p[r][2] + bb.z; o.w = p[r][3] + bb.w;
        *(float4*)&out[gi*4] = o;
      }
    }
  }
}

extern "C" void kernel_launch(void* const* d_in, const int* in_sizes, int n_in,
                              void* d_out, int out_size, void* d_ws, size_t ws_size,
                              hipStream_t stream){
  const float* x    = (const float*)d_in[0];
  const float* cl   = (const float*)d_in[1];
  const int*   ei   = (const int*)d_in[2];
  const int*   batch= (const int*)d_in[3];
  const float* W1   = (const float*)d_in[4];
  const float* a1s  = (const float*)d_in[5];
  const float* a1d  = (const float*)d_in[6];
  const float* b1   = (const float*)d_in[7];
  const float* g1   = (const float*)d_in[8];
  const float* be1  = (const float*)d_in[9];
  const float* W2   = (const float*)d_in[10];
  const float* a2s  = (const float*)d_in[11];
  const float* a2d  = (const float*)d_in[12];
  const float* b2   = (const float*)d_in[13];
  const float* g2   = (const float*)d_in[14];
  const float* be2  = (const float*)d_in[15];
  const float* Wc   = (const float*)d_in[16];
  const float* bc   = (const float*)d_in[17];
  const float* Wcl1 = (const float*)d_in[18];
  const float* bcl1 = (const float*)d_in[19];
  const float* Wcl2 = (const float*)d_in[20];
  const float* bcl2 = (const float*)d_in[21];
  const int* srcE = ei;
  const int* dstE = ei + N_EDGES;
  float* out = (float*)d_out;

  char* w = (char*)d_ws;
  auto take = [&](size_t bytes)->char*{ char* p = w; w += (bytes + 255) & ~(size_t)255; return p; };
  ushort_t* h1b = (ushort_t*)take((size_t)50048*C1*2);     // padded to 782*64 rows
  ushort_t* y1b = (ushort_t*)take((size_t)N_NODES*C1*2);   // 25.6 MB bf16
  float* es1 = (float*)take((size_t)50048*NH*4);
  float* ed1 = (float*)take((size_t)50048*NH*4);
  float* es2 = (float*)take((size_t)N_NODES*4);
  float* ed2 = (float*)take((size_t)N_NODES*4);
  float* st  = (float*)take((2*C1 + 2*HID)*4);   // 2560 B, contiguous with cnt -> single memset
  int* cnt  = (int*)take((size_t)CNT_PAD*4);
  int* off  = (int*)take((size_t)(CNT_PAD+16)*4);
  int* csr  = (int*)take((size_t)N_EDGES*4);
  int* rank = (int*)take((size_t)N_EDGES*4);
  float* st1 = st;
  float* st2 = st + 2*C1;
  // alias into dead h1b region after k_agg1: h2b (6.4 MB) at 0, y2 (12.8 MB) at +8 MB
  ushort_t* h2b = h1b;
  float* y2 = (float*)((char*)h1b + ((size_t)8 << 20));

  // st (2560 B) immediately followed by cnt: one memset covers both
  hipMemsetAsync(st, 0, (size_t)(2*C1 + 2*HID)*4 + (size_t)CNT_PAD*4, stream);

  k_pre<<<NB_N1 + NB_HIST, 256, 0, stream>>>(x, W1, a1s, a1d, h1b, es1, ed1, dstE, cnt, rank);
  k_scan<<<1, 1024, 0, stream>>>(cnt, off);
  k_scatter<<<(N_EDGES + 1023)/1024, 256, 0, stream>>>(srcE, dstE, rank, off, csr);

  k_agg1<<<(N_NODES+3)/4, 256, 0, stream>>>(h1b, es1, ed1, off, csr, b1, y1b);
  k_colstats1<<<NB_CS, 256, 0, stream>>>(y1b, st1);
  k_gemm2<<<(N_NODES+63)/64, 256, 0, stream>>>(y1b, W2, st1, g1, be1, a2s, a2d, h2b, es2, ed2);
  k_agg2<<<(N_NODES+3)/4, 256, 0, stream>>>(h2b, es2, ed2, off, csr, b2, y2);
  k_colstats2<<<NB_CS, 256, 0, stream>>>(y2, st2);
  k_final<<<(N_NODES+63)/64, 256, 0, stream>>>(y2, st2, g2, be2, batch, cl, Wc, bc, Wcl1, bcl1, Wcl2, bcl2, out);
}

// Round 17
// 284.135 us; speedup vs baseline: 1.9074x; 1.2533x over previous
//
#include <hip/hip_runtime.h>

#define N_NODES   50000
#define N_EDGES   800000
#define G_GRAPHS  512
#define D_IN      10
#define D_CL      6
#define HID       64
#define NH        4
#define C1        256   // NH*HID
#define D_OUT     4
#define BN_EPS    1e-5f
#define CNT_PAD   53248  // 52*1024, padded count buffer for vectorized scan
#define NB_N1     782    // node1 sub-grid: 782*64 = 50048 >= 50000
#define NB_HIST   391    // hist sub-grid: 391*2048 = 800768 >= 800000 (8 edges/thread)
#define NB_CS     96     // colstats blocks: per-address atomic chain = 96

typedef unsigned short ushort_t;
typedef unsigned int uint_t;

__device__ __forceinline__ float leaky(float x){ return x > 0.f ? x : 0.2f*x; }
__device__ __forceinline__ ushort_t f2bf(float f){
  unsigned u = __float_as_uint(f);
  return (ushort_t)((u + 0x7fffu + ((u >> 16) & 1u)) >> 16);
}
__device__ __forceinline__ float bflo(uint_t u){ return __uint_as_float(u << 16); }
__device__ __forceinline__ float bfhi(uint_t u){ return __uint_as_float(u & 0xffff0000u); }
__device__ __forceinline__ uint_t pack2(float a, float b){
  return (uint_t)f2bf(a) | ((uint_t)f2bf(b) << 16);
}

// ---------------- K_pre: grid-fused {h1 = x@W1 + analytic logits} || {8-edge/thread hist+rank} ----------------
__global__ __launch_bounds__(256) void k_pre(const float* __restrict__ x,
    const float* __restrict__ W1, const float* __restrict__ a1s, const float* __restrict__ a1d,
    ushort_t* __restrict__ h1b, float* __restrict__ es1, float* __restrict__ ed1,
    const int* __restrict__ dstE, int* __restrict__ cnt, int* __restrict__ rank){
  if (blockIdx.x >= NB_N1){
    int base = (blockIdx.x - NB_N1)*2048 + threadIdx.x;
    #pragma unroll
    for (int u = 0; u < 8; ++u){
      int e = base + u*256;
      if (e < N_EDGES){
        rank[e] = atomicAdd(&cnt[dstE[e]], 1);
      }
    }
    return;
  }
  __shared__ float As[64][12];          // x tile, pad 10->12
  __shared__ float ahat[2][D_IN][NH];
  int t = threadIdx.x;
  long i0 = (long)blockIdx.x * 64;
  for (int idx = t; idx < 64*D_IN; idx += 256){
    int r = idx / D_IN, k = idx - r*D_IN;
    long gi = i0 + r;
    As[r][k] = (gi < N_NODES) ? x[gi*D_IN + k] : 0.f;
  }
  int cp = t & 127, half = t >> 7;
  float w1r0[D_IN], w1r1[D_IN];
  #pragma unroll
  for (int k = 0; k < D_IN; ++k){
    float2 v = *(const float2*)&W1[k*C1 + 2*cp];
    w1r0[k] = v.x; w1r1[k] = v.y;
  }
  if (t < 2*D_IN*NH){                  // 80 threads compute ahat (from global; no LDS conflicts)
    int which = (t >= D_IN*NH) ? 1 : 0;
    int r = which ? t - D_IN*NH : t;
    int k = r >> 2, h = r & 3;
    const float* av = which ? a1d : a1s;
    const float* wrow = &W1[k*C1 + h*64];
    const float* arow = &av[h*64];
    float s = 0.f;
    #pragma unroll
    for (int d = 0; d < 64; d += 4){
      float4 wv = *(const float4*)&wrow[d];
      float4 avv = *(const float4*)&arow[d];
      s += wv.x*avv.x + wv.y*avv.y + wv.z*avv.z + wv.w*avv.w;
    }
    ahat[which][k][h] = s;
  }
  __syncthreads();
  uint_t* h1u = (uint_t*)h1b;
  for (int r = half; r < 64; r += 2){
    long gi = i0 + r;
    if (gi >= N_NODES) break;
    float acc0 = 0.f, acc1 = 0.f;
    #pragma unroll
    for (int k = 0; k < D_IN; ++k){
      float xv = As[r][k];
      acc0 += xv*w1r0[k];
      acc1 += xv*w1r1[k];
    }
    h1u[gi*128 + cp] = pack2(acc0, acc1);
  }
  {
    int nn = t >> 2, h = t & 3;
    long gi = i0 + nn;
    if (gi < N_NODES){
      float s = 0.f, d_ = 0.f;
      #pragma unroll
      for (int k = 0; k < D_IN; ++k){
        float xv = As[nn][k];
        s  += xv*ahat[0][k][h];
        d_ += xv*ahat[1][k][h];
      }
      es1[gi*NH + h] = s;
      ed1[gi*NH + h] = d_;
    }
  }
}

// single-block vectorized exclusive scan of cnt -> off
__global__ __launch_bounds__(1024) void k_scan(const int* __restrict__ cnt, int* __restrict__ off){
  __shared__ int sh[1024];
  int t = threadIdx.x;
  int4 v[13];
  const int4* c4 = (const int4*)cnt;
  int base4 = t*13;
  int tsum = 0;
  #pragma unroll
  for (int k = 0; k < 13; ++k){
    v[k] = c4[base4 + k];
    tsum += v[k].x + v[k].y + v[k].z + v[k].w;
  }
  sh[t] = tsum;
  __syncthreads();
  for (int o = 1; o < 1024; o <<= 1){
    int xv = (t >= o) ? sh[t-o] : 0;
    __syncthreads();
    sh[t] += xv;
    __syncthreads();
  }
  int run = sh[t] - tsum;
  int4* o4 = (int4*)off;
  #pragma unroll
  for (int k = 0; k < 13; ++k){
    int i = t*52 + k*4;
    int4 w_;
    w_.x = run; run += v[k].x;
    w_.y = run; run += v[k].y;
    w_.z = run; run += v[k].z;
    w_.w = run; run += v[k].w;
    if (i + 3 < N_NODES) o4[base4 + k] = w_;
    else {
      if (i+0 < N_NODES) off[i+0] = w_.x;
      if (i+1 < N_NODES) off[i+1] = w_.y;
      if (i+2 < N_NODES) off[i+2] = w_.z;
      if (i+3 < N_NODES) off[i+3] = w_.w;
    }
  }
  if (t == 0) off[N_NODES] = N_EDGES;
}

// atomic-free scatter, 4 edges/thread
__global__ __launch_bounds__(256) void k_scatter(const int* __restrict__ src, const int* __restrict__ dst,
                          const int* __restrict__ rank, const int* __restrict__ off,
                          int* __restrict__ csr){
  int base = blockIdx.x*1024 + threadIdx.x;
  #pragma unroll
  for (int u = 0; u < 4; ++u){
    int e = base + u*256;
    if (e < N_EDGES) csr[off[dst[e]] + rank[e]] = src[e];
  }
}

// ---------------- K3: layer-1 GAT aggregation ----------------
__global__ __launch_bounds__(256) void k_agg1(const ushort_t* __restrict__ h1b,
    const float* __restrict__ es1, const float* __restrict__ ed1,
    const int* __restrict__ off, const int* __restrict__ csr,
    const float* __restrict__ b1, ushort_t* __restrict__ y1b){
  int lane = threadIdx.x & 63, wid = threadIdx.x >> 6;
  int i = blockIdx.x*4 + wid;
  if (i >= N_NODES) return;
  int lh = lane & 31, hf = lane >> 5;
  int headO = lh >> 3;
  int h    = lane & 3;
  int e    = lane >> 2;
  float4 edv4 = *(const float4*)&ed1[i*NH];
  float4 esv4 = *(const float4*)&es1[i*NH];
  float edh = (headO==0)?edv4.x:(headO==1)?edv4.y:(headO==2)?edv4.z:edv4.w;
  float esS = (headO==0)?esv4.x:(headO==1)?esv4.y:(headO==2)?esv4.z:esv4.w;
  float edw = (h==0)?edv4.x:(h==1)?edv4.y:(h==2)?edv4.z:edv4.w;
  int start = off[i], end = off[i+1];
  const uint4* h1v4 = (const uint4*)h1b;
  float wS = (hf == 0) ? __expf(leaky(esS + edh)) : 0.f;
  float ssum = wS;
  uint4 hv = h1v4[(long)i*32 + lh];
  float a0 = bflo(hv.x)*wS, a1 = bfhi(hv.x)*wS, a2 = bflo(hv.y)*wS, a3 = bfhi(hv.y)*wS;
  float a4 = bflo(hv.z)*wS, a5 = bfhi(hv.z)*wS, a6 = bflo(hv.w)*wS, a7 = bfhi(hv.w)*wS;
  for (int j0 = start; j0 < end; j0 += 16){
    int nj = end - j0; if (nj > 16) nj = 16;
    int ce = (e < nj) ? e : nj - 1;
    int sE = csr[j0 + ce];
    float wv = (e < nj) ? __expf(leaky(es1[sE*NH + h] + edw)) : 0.f;
    int jj = 0;
    for (; jj + 8 <= nj; jj += 8){
      int c0 = (jj+0+hf)<<2, c1 = (jj+2+hf)<<2, c2 = (jj+4+hf)<<2, c3 = (jj+6+hf)<<2;
      int s0 = __shfl(sE, c0);
      int s1 = __shfl(sE, c1);
      int s2 = __shfl(sE, c2);
      int s3 = __shfl(sE, c3);
      uint4 r0 = h1v4[(long)s0*32 + lh];
      uint4 r1 = h1v4[(long)s1*32 + lh];
      uint4 r2 = h1v4[(long)s2*32 + lh];
      uint4 r3 = h1v4[(long)s3*32 + lh];
      float w0 = __shfl(wv, c0 | headO);
      float w1 = __shfl(wv, c1 | headO);
      float w2 = __shfl(wv, c2 | headO);
      float w3 = __shfl(wv, c3 | headO);
      a0 += bflo(r0.x)*w0; a1 += bfhi(r0.x)*w0; a2 += bflo(r0.y)*w0; a3 += bfhi(r0.y)*w0;
      a4 += bflo(r0.z)*w0; a5 += bfhi(r0.z)*w0; a6 += bflo(r0.w)*w0; a7 += bfhi(r0.w)*w0;
      a0 += bflo(r1.x)*w1; a1 += bfhi(r1.x)*w1; a2 += bflo(r1.y)*w1; a3 += bfhi(r1.y)*w1;
      a4 += bflo(r1.z)*w1; a5 += bfhi(r1.z)*w1; a6 += bflo(r1.w)*w1; a7 += bfhi(r1.w)*w1;
      a0 += bflo(r2.x)*w2; a1 += bfhi(r2.x)*w2; a2 += bflo(r2.y)*w2; a3 += bfhi(r2.y)*w2;
      a4 += bflo(r2.z)*w2; a5 += bfhi(r2.z)*w2; a6 += bflo(r2.w)*w2; a7 += bfhi(r2.w)*w2;
      a0 += bflo(r3.x)*w3; a1 += bfhi(r3.x)*w3; a2 += bflo(r3.y)*w3; a3 += bfhi(r3.y)*w3;
      a4 += bflo(r3.z)*w3; a5 += bfhi(r3.z)*w3; a6 += bflo(r3.w)*w3; a7 += bfhi(r3.w)*w3;
      ssum += w0 + w1 + w2 + w3;
    }
    for (; jj < nj; jj += 2){
      int slot = jj + hf;
      int slc = (slot < nj) ? slot : nj - 1;
      int cc = slc << 2;
      int s = __shfl(sE, cc);
      float w = __shfl(wv, cc | headO);
      if (slot >= nj) w = 0.f;
      uint4 r = h1v4[(long)s*32 + lh];
      a0 += bflo(r.x)*w; a1 += bfhi(r.x)*w; a2 += bflo(r.y)*w; a3 += bfhi(r.y)*w;
      a4 += bflo(r.z)*w; a5 += bfhi(r.z)*w; a6 += bflo(r.w)*w; a7 += bfhi(r.w)*w;
      ssum += w;
    }
  }
  a0 += __shfl_xor(a0,32); a1 += __shfl_xor(a1,32); a2 += __shfl_xor(a2,32); a3 += __shfl_xor(a3,32);
  a4 += __shfl_xor(a4,32); a5 += __shfl_xor(a5,32); a6 += __shfl_xor(a6,32); a7 += __shfl_xor(a7,32);
  ssum += __shfl_xor(ssum,32);
  if (hf == 0){
    float inv = 1.f/(ssum + 1e-16f);
    float4 bb0 = *(const float4*)&b1[8*lh];
    float4 bb1 = *(const float4*)&b1[8*lh+4];
    uint4 o;
    o.x = pack2(a0*inv + bb0.x, a1*inv + bb0.y);
    o.y = pack2(a2*inv + bb0.z, a3*inv + bb0.w);
    o.z = pack2(a4*inv + bb1.x, a5*inv + bb1.y);
    o.w = pack2(a6*inv + bb1.z, a7*inv + bb1.w);
    ((uint4*)y1b)[(long)i*32 + lh] = o;
  }
}

// ---------------- BN1 column stats (bf16, C1 ch): 96 blocks, 8-deep ILP, 1 atomic/ch/block ----------------
#define CS1_ACC(U) { float xa = bflo(U.x), xb = bfhi(U.x), xc = bflo(U.y), xd = bfhi(U.y); \
  s0 += xa; q0 += xa*xa; s1 += xb; q1 += xb*xb; s2 += xc; q2 += xc*xc; s3 += xd; q3 += xd*xd; }
__global__ __launch_bounds__(256) void k_colstats1(const ushort_t* __restrict__ y, float* __restrict__ st){
  __shared__ float cs[3*64*8];
  const uint2* yv = (const uint2*)y;   // row = 64 x uint2 (4 bf16 each)
  int t = threadIdx.x;
  int c2 = t & 63, rg = t >> 6;        // 4 row-groups
  const int rpb = (N_NODES + NB_CS - 1)/NB_CS;   // 521
  int r0 = blockIdx.x*rpb;
  int r1 = r0 + rpb; if (r1 > N_NODES) r1 = N_NODES;
  float s0=0,s1=0,s2=0,s3=0,q0=0,q1=0,q2=0,q3=0;
  int r = r0 + rg;
  for (; r + 28 < r1; r += 32){        // 8 independent loads in flight
    uint2 u0 = yv[(long)(r+ 0)*64 + c2];
    uint2 u1 = yv[(long)(r+ 4)*64 + c2];
    uint2 u2 = yv[(long)(r+ 8)*64 + c2];
    uint2 u3 = yv[(long)(r+12)*64 + c2];
    uint2 u4 = yv[(long)(r+16)*64 + c2];
    uint2 u5 = yv[(long)(r+20)*64 + c2];
    uint2 u6 = yv[(long)(r+24)*64 + c2];
    uint2 u7 = yv[(long)(r+28)*64 + c2];
    CS1_ACC(u0) CS1_ACC(u1) CS1_ACC(u2) CS1_ACC(u3)
    CS1_ACC(u4) CS1_ACC(u5) CS1_ACC(u6) CS1_ACC(u7)
  }
  for (; r < r1; r += 4){
    uint2 u = yv[(long)r*64 + c2];
    CS1_ACC(u)
  }
  if (rg > 0){
    float* p = &cs[((rg-1)*64 + c2)*8];
    p[0]=s0; p[1]=s1; p[2]=s2; p[3]=s3; p[4]=q0; p[5]=q1; p[6]=q2; p[7]=q3;
  }
  __syncthreads();
  if (rg == 0){
    #pragma unroll
    for (int g = 0; g < 3; ++g){
      float* p = &cs[(g*64 + c2)*8];
      s0+=p[0]; s1+=p[1]; s2+=p[2]; s3+=p[3]; q0+=p[4]; q1+=p[5]; q2+=p[6]; q3+=p[7];
    }
    int c = c2*4;
    atomicAdd(&st[c+0], s0);  atomicAdd(&st[C1+c+0], q0);
    atomicAdd(&st[c+1], s1);  atomicAdd(&st[C1+c+1], q1);
    atomicAdd(&st[c+2], s2);  atomicAdd(&st[C1+c+2], q2);
    atomicAdd(&st[c+3], s3);  atomicAdd(&st[C1+c+3], q3);
  }
}

// ---------------- BN2 column stats (f32, HID ch): 96 blocks, 8-deep ILP, 1 atomic/ch/block ----------------
#define CS2_ACC(V) { s0 += V.x; q0 += V.x*V.x; s1 += V.y; q1 += V.y*V.y; \
  s2 += V.z; q2 += V.z*V.z; s3 += V.w; q3 += V.w*V.w; }
__global__ __launch_bounds__(256) void k_colstats2(const float* __restrict__ y, float* __restrict__ st){
  __shared__ float cs[15*16*8];
  const float4* yv = (const float4*)y;   // row = 16 x float4
  int t = threadIdx.x;
  int c4 = t & 15, rg = t >> 4;          // 16 row-groups
  const int rpb = (N_NODES + NB_CS - 1)/NB_CS;   // 521
  int r0 = blockIdx.x*rpb;
  int r1 = r0 + rpb; if (r1 > N_NODES) r1 = N_NODES;
  float s0=0,s1=0,s2=0,s3=0,q0=0,q1=0,q2=0,q3=0;
  int r = r0 + rg;
  for (; r + 112 < r1; r += 128){        // 8 independent loads in flight
    float4 v0 = yv[(long)(r+  0)*16 + c4];
    float4 v1 = yv[(long)(r+ 16)*16 + c4];
    float4 v2 = yv[(long)(r+ 32)*16 + c4];
    float4 v3 = yv[(long)(r+ 48)*16 + c4];
    float4 v4 = yv[(long)(r+ 64)*16 + c4];
    float4 v5 = yv[(long)(r+ 80)*16 + c4];
    float4 v6 = yv[(long)(r+ 96)*16 + c4];
    float4 v7 = yv[(long)(r+112)*16 + c4];
    CS2_ACC(v0) CS2_ACC(v1) CS2_ACC(v2) CS2_ACC(v3)
    CS2_ACC(v4) CS2_ACC(v5) CS2_ACC(v6) CS2_ACC(v7)
  }
  for (; r < r1; r += 16){
    float4 v = yv[(long)r*16 + c4];
    CS2_ACC(v)
  }
  if (rg > 0){
    float* p = &cs[((rg-1)*16 + c4)*8];
    p[0]=s0; p[1]=s1; p[2]=s2; p[3]=s3; p[4]=q0; p[5]=q1; p[6]=q2; p[7]=q3;
  }
  __syncthreads();
  if (rg == 0){
    #pragma unroll
    for (int g = 0; g < 15; ++g){
      float* p = &cs[(g*16 + c4)*8];
      s0+=p[0]; s1+=p[1]; s2+=p[2]; s3+=p[3]; q0+=p[4]; q1+=p[5]; q2+=p[6]; q3+=p[7];
    }
    int c = c4*4;
    atomicAdd(&st[c+0], s0);  atomicAdd(&st[HID+c+0], q0);
    atomicAdd(&st[c+1], s1);  atomicAdd(&st[HID+c+1], q1);
    atomicAdd(&st[c+2], s2);  atomicAdd(&st[HID+c+2], q2);
    atomicAdd(&st[c+3], s3);  atomicAdd(&st[HID+c+3], q3);
  }
}

// ---------------- K6: h2 = relu(bn(y1)) @ W2 (bf16 out) + fused es2/ed2; BN prep inlined ----------------
__global__ __launch_bounds__(256) void k_gemm2(const ushort_t* __restrict__ y1b, const float* __restrict__ W2,
    const float* __restrict__ st1, const float* __restrict__ g1, const float* __restrict__ be1,
    const float* __restrict__ a2s, const float* __restrict__ a2d,
    ushort_t* __restrict__ h2b, float* __restrict__ es2, float* __restrict__ ed2){
  __shared__ float As[64][68];
  __shared__ float Bs[64][64];
  __shared__ float as_s[HID], ad_s[HID];
  __shared__ float ss_s[2*C1];
  int t = threadIdx.x;
  if (t < HID){ as_s[t] = a2s[t]; ad_s[t] = a2d[t]; }
  {
    float mean = st1[t] / (float)N_NODES;
    float var  = st1[C1 + t] / (float)N_NODES - mean*mean;
    float sc = g1[t] * rsqrtf(var + BN_EPS);
    ss_s[t] = sc;
    ss_s[C1 + t] = be1[t] - mean*sc;
  }
  int tx = t & 15, ty = t >> 4;
  long i0 = (long)blockIdx.x * 64;
  float acc[4][4] = {};
  __syncthreads();
  for (int kc = 0; kc < C1; kc += 64){
    const uint_t* yu = (const uint_t*)y1b;
    for (int idx = t; idx < 64*32; idx += 256){
      int r = idx >> 5, k2 = idx & 31;
      long gi = i0 + r;
      int k = kc + k2*2;
      float v0 = 0.f, v1 = 0.f;
      if (gi < N_NODES){
        uint_t u = yu[gi*128 + (k >> 1)];
        v0 = fmaxf(bflo(u)*ss_s[k]   + ss_s[C1+k],   0.f);
        v1 = fmaxf(bfhi(u)*ss_s[k+1] + ss_s[C1+k+1], 0.f);
      }
      As[r][k2*2]   = v0;
      As[r][k2*2+1] = v1;
    }
    for (int idx = t; idx < 64*64; idx += 256){
      Bs[idx >> 6][idx & 63] = W2[(kc + (idx >> 6))*HID + (idx & 63)];
    }
    __syncthreads();
    #pragma unroll 4
    for (int kk = 0; kk < 64; kk += 4){
      float4 va0 = *(float4*)&As[4*ty+0][kk];
      float4 va1 = *(float4*)&As[4*ty+1][kk];
      float4 va2 = *(float4*)&As[4*ty+2][kk];
      float4 va3 = *(float4*)&As[4*ty+3][kk];
      float4 vb0 = *(float4*)&Bs[kk+0][4*tx];
      float4 vb1 = *(float4*)&Bs[kk+1][4*tx];
      float4 vb2 = *(float4*)&Bs[kk+2][4*tx];
      float4 vb3 = *(float4*)&Bs[kk+3][4*tx];
      acc[0][0] += va0.x*vb0.x + va0.y*vb1.x + va0.z*vb2.x + va0.w*vb3.x;
      acc[0][1] += va0.x*vb0.y + va0.y*vb1.y + va0.z*vb2.y + va0.w*vb3.y;
      acc[0][2] += va0.x*vb0.z + va0.y*vb1.z + va0.z*vb2.z + va0.w*vb3.z;
      acc[0][3] += va0.x*vb0.w + va0.y*vb1.w + va0.z*vb2.w + va0.w*vb3.w;
      acc[1][0] += va1.x*vb0.x + va1.y*vb1.x + va1.z*vb2.x + va1.w*vb3.x;
      acc[1][1] += va1.x*vb0.y + va1.y*vb1.y + va1.z*vb2.y + va1.w*vb3.y;
      acc[1][2] += va1.x*vb0.z + va1.y*vb1.z + va1.z*vb2.z + va1.w*vb3.z;
      acc[1][3] += va1.x*vb0.w + va1.y*vb1.w + va1.z*vb2.w + va1.w*vb3.w;
      acc[2][0] += va2.x*vb0.x + va2.y*vb1.x + va2.z*vb2.x + va2.w*vb3.x;
      acc[2][1] += va2.x*vb0.y + va2.y*vb1.y + va2.z*vb2.y + va2.w*vb3.y;
      acc[2][2] += va2.x*vb0.z + va2.y*vb1.z + va2.z*vb2.z + va2.w*vb3.z;
      acc[2][3] += va2.x*vb0.w + va2.y*vb1.w + va2.z*vb2.w + va2.w*vb3.w;
      acc[3][0] += va3.x*vb0.x + va3.y*vb1.x + va3.z*vb2.x + va3.w*vb3.x;
      acc[3][1] += va3.x*vb0.y + va3.y*vb1.y + va3.z*vb2.y + va3.w*vb3.y;
      acc[3][2] += va3.x*vb0.z + va3.y*vb1.z + va3.z*vb2.z + va3.w*vb3.z;
      acc[3][3] += va3.x*vb0.w + va3.y*vb1.w + va3.z*vb2.w + va3.w*vb3.w;
    }
    __syncthreads();
  }
  #pragma unroll
  for (int rr = 0; rr < 4; ++rr){
    long gi = i0 + 4*ty + rr;
    if (gi < N_NODES){
      uint_t p0 = pack2(acc[rr][0], acc[rr][1]);
      uint_t p1 = pack2(acc[rr][2], acc[rr][3]);
      *(uint2*)&h2b[gi*HID + 4*tx] = make_uint2(p0, p1);
      float ps = acc[rr][0]*as_s[4*tx+0] + acc[rr][1]*as_s[4*tx+1]
               + acc[rr][2]*as_s[4*tx+2] + acc[rr][3]*as_s[4*tx+3];
      float pd = acc[rr][0]*ad_s[4*tx+0] + acc[rr][1]*ad_s[4*tx+1]
               + acc[rr][2]*ad_s[4*tx+2] + acc[rr][3]*ad_s[4*tx+3];
      #pragma unroll
      for (int o = 8; o >= 1; o >>= 1){ ps += __shfl_xor(ps,o); pd += __shfl_xor(pd,o); }
      if (tx == 0){ es2[gi] = ps; ed2[gi] = pd; }
    }
  }
}

// ---------------- K7: layer-2 GAT aggregation (f32 output) ----------------
__global__ __launch_bounds__(256) void k_agg2(const ushort_t* __restrict__ h2b,
    const float* __restrict__ es2, const float* __restrict__ ed2,
    const int* __restrict__ off, const int* __restrict__ csr,
    const float* __restrict__ b2, float* __restrict__ y2){
  int lane = threadIdx.x & 63, wid = threadIdx.x >> 6;
  int i = blockIdx.x*4 + wid;
  if (i >= N_NODES) return;
  int lq = lane & 15, q = lane >> 4;
  float edv = ed2[i];
  int start = off[i], end = off[i+1];
  const uint2* h2u2 = (const uint2*)h2b;
  float a0, a1, a2, a3, ssum;
  {
    float wS = (q == 0) ? __expf(leaky(es2[i] + edv)) : 0.f;
    uint2 uS = h2u2[(long)i*16 + lq];
    a0 = bflo(uS.x)*wS; a1 = bfhi(uS.x)*wS; a2 = bflo(uS.y)*wS; a3 = bfhi(uS.y)*wS;
    ssum = wS;
  }
  for (int j0 = start; j0 < end; j0 += 64){
    int nj = end - j0; if (nj > 64) nj = 64;
    int ce = (lane < nj) ? lane : nj - 1;
    int sE = csr[j0 + ce];
    float wv = (lane < nj) ? __expf(leaky(es2[sE] + edv)) : 0.f;
    int jj = 0;
    for (; jj + 16 <= nj; jj += 16){
      int c0 = jj + q, c1 = jj + 4 + q, c2 = jj + 8 + q, c3 = jj + 12 + q;
      int s0 = __shfl(sE, c0);
      int s1 = __shfl(sE, c1);
      int s2 = __shfl(sE, c2);
      int s3 = __shfl(sE, c3);
      uint2 r0 = h2u2[(long)s0*16 + lq];
      uint2 r1 = h2u2[(long)s1*16 + lq];
      uint2 r2 = h2u2[(long)s2*16 + lq];
      uint2 r3 = h2u2[(long)s3*16 + lq];
      float w0 = __shfl(wv, c0);
      float w1 = __shfl(wv, c1);
      float w2 = __shfl(wv, c2);
      float w3 = __shfl(wv, c3);
      a0 += bflo(r0.x)*w0; a1 += bfhi(r0.x)*w0; a2 += bflo(r0.y)*w0; a3 += bfhi(r0.y)*w0;
      a0 += bflo(r1.x)*w1; a1 += bfhi(r1.x)*w1; a2 += bflo(r1.y)*w1; a3 += bfhi(r1.y)*w1;
      a0 += bflo(r2.x)*w2; a1 += bfhi(r2.x)*w2; a2 += bflo(r2.y)*w2; a3 += bfhi(r2.y)*w2;
      a0 += bflo(r3.x)*w3; a1 += bfhi(r3.x)*w3; a2 += bflo(r3.y)*w3; a3 += bfhi(r3.y)*w3;
      ssum += w0 + w1 + w2 + w3;
    }
    for (; jj < nj; jj += 4){
      int slot = jj + q;
      int slc = (slot < nj) ? slot : nj - 1;
      int s = __shfl(sE, slc);
      float w = __shfl(wv, slc);
      if (slot >= nj) w = 0.f;
      uint2 r = h2u2[(long)s*16 + lq];
      a0 += bflo(r.x)*w; a1 += bfhi(r.x)*w; a2 += bflo(r.y)*w; a3 += bfhi(r.y)*w;
      ssum += w;
    }
  }
  a0 += __shfl_xor(a0,16); a1 += __shfl_xor(a1,16); a2 += __shfl_xor(a2,16); a3 += __shfl_xor(a3,16);
  ssum += __shfl_xor(ssum,16);
  a0 += __shfl_xor(a0,32); a1 += __shfl_xor(a1,32); a2 += __shfl_xor(a2,32); a3 += __shfl_xor(a3,32);
  ssum += __shfl_xor(ssum,32);
  if (q == 0){
    float inv = 1.f/(ssum + 1e-16f);
    float4 bb = *(const float4*)&b2[4*lq];
    float4 o;
    o.x = a0*inv + bb.x; o.y = a1*inv + bb.y;
    o.z = a2*inv + bb.z; o.w = a3*inv + bb.w;
    ((float4*)y2)[(long)i*16 + lq] = o;
  }
}

// ---------------- final: tiled GEMM, BN2 prep + climber MLP inlined ----------------
__global__ __launch_bounds__(256) void k_final(const float* __restrict__ y2,
    const float* __restrict__ st2, const float* __restrict__ g2, const float* __restrict__ be2,
    const int* __restrict__ batch,
    const float* __restrict__ cl, const float* __restrict__ Wc, const float* __restrict__ bc,
    const float* __restrict__ Wcl1, const float* __restrict__ bcl1,
    const float* __restrict__ Wcl2, const float* __restrict__ bcl2,
    float* __restrict__ out){
  __shared__ float As[64][132];
  __shared__ float Bs[128][64];
  __shared__ float ss2s[2*HID];
  __shared__ float b1s[HID];
  __shared__ float W2s[HID*D_OUT];
  __shared__ float Wcs[D_CL*HID];
  __shared__ float bcs[HID];
  int t = threadIdx.x;
  long i0 = (long)blockIdx.x * 64;
  if (t < HID){
    float mean = st2[t] / (float)N_NODES;
    float var  = st2[HID + t] / (float)N_NODES - mean*mean;
    float sc = g2[t] * rsqrtf(var + BN_EPS);
    ss2s[t] = sc;
    ss2s[HID + t] = be2[t] - mean*sc;
  }
  if (t >= 64 && t < 128) bcs[t-64] = bc[t-64];
  if (t >= 128 && t < 192) b1s[t-128] = bcl1[t-128];
  W2s[t] = Wcl2[t];
  for (int idx = t; idx < D_CL*HID; idx += 256) Wcs[idx] = Wc[idx];
  __syncthreads();
  const float2* y2v = (const float2*)y2;
  #pragma unroll
  for (int ii = 0; ii < 8; ++ii){
    int idx = t + 256*ii;
    int r = idx >> 5, k2 = idx & 31;
    long gi = i0 + r;
    float2 v = make_float2(0.f, 0.f);
    if (gi < N_NODES) v = y2v[gi*32 + k2];
    int k = k2*2;
    As[r][k]   = fmaxf(v.x*ss2s[k]   + ss2s[HID+k],   0.f);
    As[r][k+1] = fmaxf(v.y*ss2s[k+1] + ss2s[HID+k+1], 0.f);
  }
  #pragma unroll
  for (int ii = 0; ii < 8; ++ii){
    int idx = t + 256*ii;
    int r = idx >> 5, k2 = idx & 31;
    long gi = i0 + r;
    int k = k2*2;
    float c0 = 0.f, c1 = 0.f;
    if (gi < N_NODES){
      int g = batch[gi];
      const float* cg = cl + (long)g*D_CL;
      c0 = bcs[k]; c1 = bcs[k+1];
      #pragma unroll
      for (int kk = 0; kk < D_CL; ++kk){
        float clv = cg[kk];
        c0 += clv*Wcs[kk*HID + k];
        c1 += clv*Wcs[kk*HID + k+1];
      }
      c0 = fmaxf(c0, 0.f); c1 = fmaxf(c1, 0.f);
    }
    As[r][HID + k]   = c0;
    As[r][HID + k+1] = c1;
  }
  #pragma unroll
  for (int ii = 0; ii < 8; ++ii){
    int idx = t + 256*ii;
    int kk = idx >> 4, c4 = idx & 15;
    *(float4*)&Bs[kk][c4*4] = *(const float4*)&Wcl1[kk*64 + c4*4];
  }
  __syncthreads();
  int tx = t & 15, ty = t >> 4;
  float acc[4][4] = {};
  #pragma unroll 4
  for (int kk = 0; kk < 2*HID; kk += 4){
    float4 a0 = *(float4*)&As[4*ty+0][kk];
    float4 a1 = *(float4*)&As[4*ty+1][kk];
    float4 a2 = *(float4*)&As[4*ty+2][kk];
    float4 a3 = *(float4*)&As[4*ty+3][kk];
    float4 b0 = *(float4*)&Bs[kk+0][4*tx];
    float4 b1 = *(float4*)&Bs[kk+1][4*tx];
    float4 b2 = *(float4*)&Bs[kk+2][4*tx];
    float4 b3 = *(float4*)&Bs[kk+3][4*tx];
    acc[0][0] += a0.x*b0.x + a0.y*b1.x + a0.z*b2.x + a0.w*b3.x;
    acc[0][1] += a0.x*b0.y + a0.y*b1.y + a0.z*b2.y + a0.w*b3.y;
    acc[0][2] += a0.x*b0.z + a0.y*b1.z + a0.z*b2.z + a0.w*b3.z;
    acc[0][3] += a0.x*b0.w + a0.y*b1.w + a0.z*b2.w + a0.w*b3.w;
    acc[1][0] += a1.x*b0.x + a1.y*b1.x + a1.z*b2.x + a1.w*b3.x;
    acc[1][1] += a1.x*b0.y + a1.y*b1.y + a1.z*b2.y + a1.w*b3.y;
    acc[1][2] += a1.x*b0.z + a1.y*b1.z + a1.z*b2.z + a1.w*b3.z;
    acc[1][3] += a1.x*b0.w + a1.y*b1.w + a1.z*b2.w + a1.w*b3.w;
    acc[2][0] += a2.x*b0.x + a2.y*b1.x + a2.z*b2.x + a2.w*b3.x;
    acc[2][1] += a2.x*b0.y + a2.y*b1.y + a2.z*b2.y + a2.w*b3.y;
    acc[2][2] += a2.x*b0.z + a2.y*b1.z + a2.z*b2.z + a2.w*b3.z;
    acc[2][3] += a2.x*b0.w + a2.y*b1.w + a2.z*b2.w + a2.w*b3.w;
    acc[3][0] += a3.x*b0.x + a3.y*b1.x + a3.z*b2.x + a3.w*b3.x;
    acc[3][1] += a3.x*b0.y + a3.y*b1.y + a3.z*b2.y + a3.w*b3.y;
    acc[3][2] += a3.x*b0.z + a3.y*b1.z + a3.z*b2.z + a3.w*b3.z;
    acc[3][3] += a3.x*b0.w + a3.y*b1.w + a3.z*b2.w + a3.w*b3.w;
  }
  float p[4][4];
  #pragma unroll
  for (int r = 0; r < 4; ++r){
    #pragma unroll
    for (int c = 0; c < 4; ++c)
      acc[r][c] = fmaxf(acc[r][c] + b1s[4*tx+c], 0.f);
    #pragma unroll
    for (int oc = 0; oc < 4; ++oc){
      p[r][oc] = acc[r][0]*W2s[(4*tx+0)*4+oc] + acc[r][1]*W2s[(4*tx+1)*4+oc]
               + acc[r][2]*W2s[(4*tx+2)*4+oc] + acc[r][3]*W2s[(4*tx+3)*4+oc];
    }
  }
  #pragma unroll
  for (int o = 8; o >= 1; o >>= 1){
    #pragma unroll
    for (int r = 0; r < 4; ++r){
      p[r][0] += __shfl_xor(p[r][0], o);
      p[r][1] += __shfl_xor(p[r][1], o);
      p[r][2] += __shfl_xor(p[r][2], o);
      p[r][3] += __shfl_xor(p[r][3], o);
    }
  }
  if (tx == 0){
    float4 bb = *(const float4*)bcl2;
    #pragma unroll
    for (int r = 0; r < 4; ++r){
      long gi = i0 + 4*ty + r;
      if (gi < N_NODES){
        float4 o;
        o.x = p[r][0] + bb.x; o.y = p[r][1] + bb.y;
        o.z = p[r][2] + bb.z; o.w = p[r][3] + bb.w;
        *(float4*)&out[gi*4] = o;
      }
    }
  }
}

extern "C" void kernel_launch(void* const* d_in, const int* in_sizes, int n_in,
                              void* d_out, int out_size, void* d_ws, size_t ws_size,
                              hipStream_t stream){
  const float* x    = (const float*)d_in[0];
  const float* cl   = (const float*)d_in[1];
  const int*   ei   = (const int*)d_in[2];
  const int*   batch= (const int*)d_in[3];
  const float* W1   = (const float*)d_in[4];
  const float* a1s  = (const float*)d_in[5];
  const float* a1d  = (const float*)d_in[6];
  const float* b1   = (const float*)d_in[7];
  const float* g1   = (const float*)d_in[8];
  const float* be1  = (const float*)d_in[9];
  const float* W2   = (const float*)d_in[10];
  const float* a2s  = (const float*)d_in[11];
  const float* a2d  = (const float*)d_in[12];
  const float* b2   = (const float*)d_in[13];
  const float* g2   = (const float*)d_in[14];
  const float* be2  = (const float*)d_in[15];
  const float* Wc   = (const float*)d_in[16];
  const float* bc   = (const float*)d_in[17];
  const float* Wcl1 = (const float*)d_in[18];
  const float* bcl1 = (const float*)d_in[19];
  const float* Wcl2 = (const float*)d_in[20];
  const float* bcl2 = (const float*)d_in[21];
  const int* srcE = ei;
  const int* dstE = ei + N_EDGES;
  float* out = (float*)d_out;

  char* w = (char*)d_ws;
  auto take = [&](size_t bytes)->char*{ char* p = w; w += (bytes + 255) & ~(size_t)255; return p; };
  ushort_t* h1b = (ushort_t*)take((size_t)50048*C1*2);     // padded to 782*64 rows
  ushort_t* y1b = (ushort_t*)take((size_t)N_NODES*C1*2);   // 25.6 MB bf16
  float* es1 = (float*)take((size_t)50048*NH*4);
  float* ed1 = (float*)take((size_t)50048*NH*4);
  float* es2 = (float*)take((size_t)N_NODES*4);
  float* ed2 = (float*)take((size_t)N_NODES*4);
  float* st  = (float*)take((2*C1 + 2*HID)*4);   // 2560 B, contiguous with cnt -> single memset
  int* cnt  = (int*)take((size_t)CNT_PAD*4);
  int* off  = (int*)take((size_t)(CNT_PAD+16)*4);
  int* csr  = (int*)take((size_t)N_EDGES*4);
  int* rank = (int*)take((size_t)N_EDGES*4);
  float* st1 = st;
  float* st2 = st + 2*C1;
  // alias into dead h1b region after k_agg1: h2b (6.4 MB) at 0, y2 (12.8 MB) at +8 MB
  ushort_t* h2b = h1b;
  float* y2 = (float*)((char*)h1b + ((size_t)8 << 20));

  // st (2560 B) immediately followed by cnt: one memset covers both
  hipMemsetAsync(st, 0, (size_t)(2*C1 + 2*HID)*4 + (size_t)CNT_PAD*4, stream);

  k_pre<<<NB_N1 + NB_HIST, 256, 0, stream>>>(x, W1, a1s, a1d, h1b, es1, ed1, dstE, cnt, rank);
  k_scan<<<1, 1024, 0, stream>>>(cnt, off);
  k_scatter<<<(N_EDGES + 1023)/1024, 256, 0, stream>>>(srcE, dstE, rank, off, csr);

  k_agg1<<<(N_NODES+3)/4, 256, 0, stream>>>(h1b, es1, ed1, off, csr, b1, y1b);
  k_colstats1<<<NB_CS, 256, 0, stream>>>(y1b, st1);
  k_gemm2<<<(N_NODES+63)/64, 256, 0, stream>>>(y1b, W2, st1, g1, be1, a2s, a2d, h2b, es2, ed2);
  k_agg2<<<(N_NODES+3)/4, 256, 0, stream>>>(h2b, es2, ed2, off, csr, b2, y2);
  k_colstats2<<<NB_CS, 256, 0, stream>>>(y2, st2);
  k_final<<<(N_NODES+63)/64, 256, 0, stream>>>(y2, st2, g2, be2, batch, cl, Wc, bc, Wcl1, bcl1, Wcl2, bcl2, out);
}